// Round 1
// baseline (749.409 us; speedup 1.0000x reference)
//
#include <hip/hip_runtime.h>
#include <cstdint>
#include <cstddef>

// Problem constants (fixed by setup_inputs)
#define QQ 8192       // Z*Y*X
#define CDIM 256
#define NV 9520
#define NLVL 4
#define NPTS 4
#define NHEAD 8
// levels: (h,w) = (64,112),(32,56),(16,28),(8,14); starts 0,7168,8960,9408

// ---------------- GEMM: C = A(MxK) @ B(KxN) + bias, row-major ----------------
#define BM 64
#define BNT 64
#define BK 16

__global__ __launch_bounds__(256) void gemm_bias_kernel(
    const float* __restrict__ A, int lda,
    const float* __restrict__ B, int ldb,
    const float* __restrict__ bias,
    float* __restrict__ C, int ldc, int K)
{
    __shared__ float As[BK][BM];
    __shared__ float Bs[BK][BNT];
    const int tid = threadIdx.x;
    const int tx = tid & 15, ty = tid >> 4;
    const int arow = tid >> 2;          // 0..63
    const int akq  = (tid & 3) << 2;    // 0,4,8,12
    const int brow = tid >> 4;          // 0..15
    const int bcol = (tid & 15) << 2;   // 0..60
    const float* Ab = A + (size_t)blockIdx.x * BM * lda;
    const float* Bb = B + (size_t)blockIdx.y * BNT;
    float acc[4][4] = {};
    for (int kt = 0; kt < K; kt += BK) {
        float4 av = *(const float4*)(Ab + (size_t)arow * lda + kt + akq);
        As[akq + 0][arow] = av.x;
        As[akq + 1][arow] = av.y;
        As[akq + 2][arow] = av.z;
        As[akq + 3][arow] = av.w;
        *(float4*)&Bs[brow][bcol] =
            *(const float4*)(Bb + (size_t)(kt + brow) * ldb + bcol);
        __syncthreads();
        #pragma unroll
        for (int k = 0; k < BK; ++k) {
            float4 a4 = *(const float4*)&As[k][ty << 2];
            float4 b4 = *(const float4*)&Bs[k][tx << 2];
            float a[4] = {a4.x, a4.y, a4.z, a4.w};
            float b[4] = {b4.x, b4.y, b4.z, b4.w};
            #pragma unroll
            for (int i = 0; i < 4; ++i)
                #pragma unroll
                for (int j = 0; j < 4; ++j)
                    acc[i][j] += a[i] * b[j];
        }
        __syncthreads();
    }
    const int row0 = blockIdx.x * BM + (ty << 2);
    const int col0 = blockIdx.y * BNT + (tx << 2);
    float4 bias4 = make_float4(0.f, 0.f, 0.f, 0.f);
    if (bias) bias4 = *(const float4*)(bias + col0);
    #pragma unroll
    for (int i = 0; i < 4; ++i) {
        float4 o = make_float4(acc[i][0] + bias4.x, acc[i][1] + bias4.y,
                               acc[i][2] + bias4.z, acc[i][3] + bias4.w);
        *(float4*)(C + (size_t)(row0 + i) * ldc + col0) = o;
    }
}

// ---------------- mask dtype sniffer (bool-as-u8 vs i32 vs f32) --------------
// flag: 0 = uint8, 1 = int32(0/1), 2 = float32(0.0/1.0)
__global__ void detect_mask_kernel(const unsigned int* __restrict__ m, int* flag)
{
    __shared__ int notI32, notF32;
    if (threadIdx.x == 0) { notI32 = 0; notF32 = 0; }
    __syncthreads();
    for (int i = threadIdx.x; i < 1024; i += 256) {
        unsigned v = m[i];
        if (v > 1u) notI32 = 1;
        if (v != 0u && v != 0x3F800000u) notF32 = 1;
    }
    __syncthreads();
    if (threadIdx.x == 0) *flag = (!notI32) ? 1 : ((!notF32) ? 2 : 0);
}

__device__ __forceinline__ float read_mask(const void* p, int f, size_t i)
{
    if (f == 1) return (float)((const int*)p)[i];
    if (f == 2) return ((const float*)p)[i];
    return (float)((const unsigned char*)p)[i];
}

// ---------------- softmax over L*P=16 per (b,q,h), in place ------------------
__global__ void softmax_kernel(float* __restrict__ offatt)
{
    int t = blockIdx.x * blockDim.x + threadIdx.x;   // B*Q*H = 131072
    int bq = t >> 3, h = t & 7;
    float* p = offatt + (size_t)bq * 384 + 256 + h * 16;
    float m = -3.4e38f;
    float e[16];
    #pragma unroll
    for (int i = 0; i < 16; ++i) m = fmaxf(m, p[i]);
    float s = 0.f;
    #pragma unroll
    for (int i = 0; i < 16; ++i) { e[i] = __expf(p[i] - m); s += e[i]; }
    float inv = 1.f / s;
    #pragma unroll
    for (int i = 0; i < 16; ++i) p[i] = e[i] * inv;
}

// ---------------- deformable bilinear sampling -------------------------------
// one block per (bn,q); thread = h*32+d
__global__ __launch_bounds__(256) void sample_kernel(
    const float* __restrict__ v,       // (BN, NV, 256)
    const float* __restrict__ offatt,  // (B*Q, 384): 256 off + 128 aw
    const float* __restrict__ refp,    // (BN, Q, 2)
    float* __restrict__ attn_in)       // (BN, Q, 256)
{
    const int bq = blockIdx.x;         // BN*Q
    const int bn = bq >> 13;
    const int q  = bq & (QQ - 1);
    const int b  = bn >> 2;
    __shared__ float soff[256];
    __shared__ float saw[128];
    const int tid = threadIdx.x;
    const float* oa = offatt + ((size_t)(b * QQ + q)) * 384;
    soff[tid] = oa[tid];
    if (tid < 128) saw[tid] = oa[256 + tid];
    const float rx = refp[((size_t)bn * QQ + q) * 2 + 0];
    const float ry = refp[((size_t)bn * QQ + q) * 2 + 1];
    __syncthreads();
    const int h = tid >> 5, d = tid & 31;
    const int hs[NLVL]  = {64, 32, 16, 8};
    const int wsz[NLVL] = {112, 56, 28, 14};
    const int st[NLVL]  = {0, 7168, 8960, 9408};
    const float* vb = v + (size_t)bn * NV * CDIM + h * 32 + d;
    float accv = 0.f;
    #pragma unroll
    for (int l = 0; l < NLVL; ++l) {
        const int hh = hs[l], ww = wsz[l], s = st[l];
        const float fx = rx * ww - 0.5f;
        const float fy = ry * hh - 0.5f;
        #pragma unroll
        for (int p = 0; p < NPTS; ++p) {
            const int oi = ((h * NLVL + l) * NPTS + p) * 2;
            const float x = fx + soff[oi];
            const float y = fy + soff[oi + 1];
            const float aw = saw[h * 16 + l * 4 + p];
            const float x0f = floorf(x), y0f = floorf(y);
            const float lx = x - x0f, ly = y - y0f;
            const int x0 = (int)x0f, y0 = (int)y0f;
            const int x1 = x0 + 1, y1 = y0 + 1;
            const bool vx0 = (x0 >= 0) & (x0 < ww);
            const bool vx1 = (x1 >= 0) & (x1 < ww);
            const bool vy0 = (y0 >= 0) & (y0 < hh);
            const bool vy1 = (y1 >= 0) & (y1 < hh);
            float g00 = 0.f, g01 = 0.f, g10 = 0.f, g11 = 0.f;
            if (vy0 & vx0) g00 = vb[(size_t)(s + y0 * ww + x0) * CDIM];
            if (vy0 & vx1) g01 = vb[(size_t)(s + y0 * ww + x1) * CDIM];
            if (vy1 & vx0) g10 = vb[(size_t)(s + y1 * ww + x0) * CDIM];
            if (vy1 & vx1) g11 = vb[(size_t)(s + y1 * ww + x1) * CDIM];
            const float w00 = (1.f - ly) * (1.f - lx);
            const float w01 = (1.f - ly) * lx;
            const float w10 = ly * (1.f - lx);
            const float w11 = ly * lx;
            accv += aw * (g00 * w00 + g01 * w01 + g10 * w10 + g11 * w11);
        }
    }
    attn_in[((size_t)bn * QQ + q) * CDIM + tid] = accv;
}

// ------------- masked reduce over N: S[b,q,:] = sum_n m_n * attn_in ----------
__global__ __launch_bounds__(256) void reduce_mask_kernel(
    const float* __restrict__ attn_in, const void* __restrict__ maskp,
    const int* __restrict__ flag,
    float* __restrict__ S, float* __restrict__ cnts)
{
    const int bq = blockIdx.x;       // B*Q
    const int b = bq >> 13, q = bq & (QQ - 1);
    const int tid = threadIdx.x;
    __shared__ float sm[4];
    if (tid < 4) {
        const int f = *flag;
        sm[tid] = read_mask(maskp, f, (size_t)(b * 4 + tid) * QQ + q);
    }
    __syncthreads();
    float acc = 0.f;
    #pragma unroll
    for (int n = 0; n < 4; ++n)
        if (sm[n] != 0.f)
            acc += attn_in[(((size_t)(b * 4 + n)) * QQ + q) * CDIM + tid];
    S[(size_t)bq * CDIM + tid] = acc;
    if (tid == 0) cnts[bq] = sm[0] + sm[1] + sm[2] + sm[3];
}

// ------------- final: out = (sm*(q+bo) + T) / max(sm,1) ----------------------
__global__ __launch_bounds__(256) void final_kernel(
    const float* __restrict__ query, const float* __restrict__ T,
    const float* __restrict__ bo, const float* __restrict__ cnts,
    float* __restrict__ out)
{
    const int bq = blockIdx.x;       // B*Q
    const int tid = threadIdx.x;
    const float sm = cnts[bq];
    const float cnt = fmaxf(sm, 1.f);
    const size_t i = (size_t)bq * CDIM + tid;
    out[i] = (sm * (query[i] + bo[tid]) + T[i]) / cnt;
}

extern "C" void kernel_launch(void* const* d_in, const int* in_sizes, int n_in,
                              void* d_out, int out_size, void* d_ws, size_t ws_size,
                              hipStream_t stream)
{
    (void)in_sizes; (void)n_in; (void)out_size; (void)ws_size;
    const float* query = (const float*)d_in[0];   // (B,Z,Y,X,C) = (16384,256)
    const float* value = (const float*)d_in[1];   // (8,9520,256)
    const float* refp  = (const float*)d_in[2];   // (8,8192,2)
    const void*  maskp = d_in[3];                 // (8,8192) bool
    const float* Wv    = (const float*)d_in[6];
    const float* bv    = (const float*)d_in[7];
    const float* Woff  = (const float*)d_in[8];
    const float* boff  = (const float*)d_in[9];
    const float* Watt  = (const float*)d_in[10];
    const float* batt  = (const float*)d_in[11];
    const float* Wo    = (const float*)d_in[12];
    const float* bo    = (const float*)d_in[13];
    float* out = (float*)d_out;
    char* ws = (char*)d_ws;

    // workspace layout (bytes)
    float* v_proj  = (float*)(ws + 0);            // 76160*256*4 = 77,987,840
    float* offatt  = (float*)(ws + 77987840);     // 16384*384*4 = 25,165,824
    float* attn_in = (float*)(ws + 103153664);    // 65536*256*4 = 67,108,864
    float* cnts    = (float*)(ws + 170262528);    // 16384*4
    int*   flag    = (int*)  (ws + 170328064);    // 4

    detect_mask_kernel<<<1, 256, 0, stream>>>((const unsigned int*)maskp, flag);

    // v = value @ Wv + bv   (76160 x 256 x 256)
    gemm_bias_kernel<<<dim3(76160 / BM, CDIM / BNT), 256, 0, stream>>>(
        value, CDIM, Wv, CDIM, bv, v_proj, CDIM, CDIM);

    // offatt[:, :256] = query @ Woff + boff   (16384 x 256 x 256)
    gemm_bias_kernel<<<dim3(16384 / BM, 256 / BNT), 256, 0, stream>>>(
        query, CDIM, Woff, 256, boff, offatt, 384, CDIM);

    // offatt[:, 256:] = query @ Watt + batt   (16384 x 128 x 256)
    gemm_bias_kernel<<<dim3(16384 / BM, 128 / BNT), 256, 0, stream>>>(
        query, CDIM, Watt, 128, batt, offatt + 256, 384, CDIM);

    softmax_kernel<<<512, 256, 0, stream>>>(offatt);

    sample_kernel<<<65536, 256, 0, stream>>>(v_proj, offatt, refp, attn_in);

    // S (reuse offatt region, flat 16384x256) + counts
    reduce_mask_kernel<<<16384, 256, 0, stream>>>(attn_in, maskp, flag, offatt, cnts);

    // T = S @ Wo  (reuse attn_in region, flat 16384x256)
    gemm_bias_kernel<<<dim3(16384 / BM, CDIM / BNT), 256, 0, stream>>>(
        offatt, CDIM, Wo, CDIM, nullptr, attn_in, CDIM, CDIM);

    final_kernel<<<16384, 256, 0, stream>>>(query, attn_in, bo, cnts, out);
}

// Round 2
// 460.889 us; speedup vs baseline: 1.6260x; 1.6260x over previous
//
#include <hip/hip_runtime.h>
#include <cstdint>
#include <cstddef>

// Problem constants (fixed by setup_inputs)
#define QQ 8192       // Z*Y*X
#define CDIM 256
#define NV 9520
#define NLVL 4
#define NPTS 4
#define NHEAD 8
// levels: (h,w) = (64,112),(32,56),(16,28),(8,14); starts 0,7168,8960,9408

// ---------------- GEMM: C = A(MxK) @ B(KxN) + bias, row-major ----------------
#define BM 64
#define BNT 64
#define BK 16

__global__ __launch_bounds__(256) void gemm_bias_kernel(
    const float* __restrict__ A, int lda,
    const float* __restrict__ B, int ldb,
    const float* __restrict__ bias,
    float* __restrict__ C, int ldc, int K)
{
    __shared__ float As[BK][BM];
    __shared__ float Bs[BK][BNT];
    const int tid = threadIdx.x;
    const int tx = tid & 15, ty = tid >> 4;
    const int arow = tid >> 2;          // 0..63
    const int akq  = (tid & 3) << 2;    // 0,4,8,12
    const int brow = tid >> 4;          // 0..15
    const int bcol = (tid & 15) << 2;   // 0..60
    const float* Ab = A + (size_t)blockIdx.x * BM * lda;
    const float* Bb = B + (size_t)blockIdx.y * BNT;
    float acc[4][4] = {};
    for (int kt = 0; kt < K; kt += BK) {
        float4 av = *(const float4*)(Ab + (size_t)arow * lda + kt + akq);
        As[akq + 0][arow] = av.x;
        As[akq + 1][arow] = av.y;
        As[akq + 2][arow] = av.z;
        As[akq + 3][arow] = av.w;
        *(float4*)&Bs[brow][bcol] =
            *(const float4*)(Bb + (size_t)(kt + brow) * ldb + bcol);
        __syncthreads();
        #pragma unroll
        for (int k = 0; k < BK; ++k) {
            float4 a4 = *(const float4*)&As[k][ty << 2];
            float4 b4 = *(const float4*)&Bs[k][tx << 2];
            float a[4] = {a4.x, a4.y, a4.z, a4.w};
            float b[4] = {b4.x, b4.y, b4.z, b4.w};
            #pragma unroll
            for (int i = 0; i < 4; ++i)
                #pragma unroll
                for (int j = 0; j < 4; ++j)
                    acc[i][j] += a[i] * b[j];
        }
        __syncthreads();
    }
    const int row0 = blockIdx.x * BM + (ty << 2);
    const int col0 = blockIdx.y * BNT + (tx << 2);
    float4 bias4 = make_float4(0.f, 0.f, 0.f, 0.f);
    if (bias) bias4 = *(const float4*)(bias + col0);
    #pragma unroll
    for (int i = 0; i < 4; ++i) {
        float4 o = make_float4(acc[i][0] + bias4.x, acc[i][1] + bias4.y,
                               acc[i][2] + bias4.z, acc[i][3] + bias4.w);
        *(float4*)(C + (size_t)(row0 + i) * ldc + col0) = o;
    }
}

// ---------------- mask dtype sniffer (bool-as-u8 vs i32 vs f32) --------------
// flag: 0 = uint8, 1 = int32(0/1), 2 = float32(0.0/1.0)
__global__ void detect_mask_kernel(const unsigned int* __restrict__ m, int* flag)
{
    __shared__ int notI32, notF32;
    if (threadIdx.x == 0) { notI32 = 0; notF32 = 0; }
    __syncthreads();
    for (int i = threadIdx.x; i < 1024; i += 256) {
        unsigned v = m[i];
        if (v > 1u) notI32 = 1;
        if (v != 0u && v != 0x3F800000u) notF32 = 1;
    }
    __syncthreads();
    if (threadIdx.x == 0) *flag = (!notI32) ? 1 : ((!notF32) ? 2 : 0);
}

__device__ __forceinline__ float read_mask(const void* p, int f, size_t i)
{
    if (f == 1) return (float)((const int*)p)[i];
    if (f == 2) return ((const float*)p)[i];
    return (float)((const unsigned char*)p)[i];
}

// ---------------- softmax over L*P=16 per (b,q,h), in place ------------------
__global__ void softmax_kernel(float* __restrict__ offatt)
{
    int t = blockIdx.x * blockDim.x + threadIdx.x;   // B*Q*H = 131072
    int bq = t >> 3, h = t & 7;
    float* p = offatt + (size_t)bq * 384 + 256 + h * 16;
    float m = -3.4e38f;
    float e[16];
    #pragma unroll
    for (int i = 0; i < 16; ++i) m = fmaxf(m, p[i]);
    float s = 0.f;
    #pragma unroll
    for (int i = 0; i < 16; ++i) { e[i] = __expf(p[i] - m); s += e[i]; }
    float inv = 1.f / s;
    #pragma unroll
    for (int i = 0; i < 16; ++i) p[i] = e[i] * inv;
}

// ---------------- deformable bilinear sampling -------------------------------
// one WAVE per (bn,q); 4 q's per 256-thread block.
// Phase 1: 128 (h,l,p) combos computed once -> LDS {int4 idx, float4 weight}.
// Phase 2: lane = h*8+d4 gathers float4 (4 channels) per corner.
__global__ __launch_bounds__(256) void sample_kernel(
    const float* __restrict__ v,       // (BN, NV, 256)
    const float* __restrict__ offatt,  // (B*Q, 384): 256 off + 128 aw
    const float* __restrict__ refp,    // (BN, Q, 2)
    float* __restrict__ attn_in)       // (BN, Q, 256)
{
    __shared__ int4   sidx[4][128];
    __shared__ float4 swt[4][128];
    const int tid  = threadIdx.x;
    const int wq   = tid >> 6;           // wave id 0..3
    const int lane = tid & 63;
    const int bq   = blockIdx.x * 4 + wq;    // BN*Q index
    const int bn   = bq >> 13;
    const int q    = bq & (QQ - 1);
    const int b    = bn >> 2;

    const float* oa = offatt + ((size_t)(b * QQ + q)) * 384;
    const float rx = refp[((size_t)bn * QQ + q) * 2 + 0];
    const float ry = refp[((size_t)bn * QQ + q) * 2 + 1];

    // ---- phase 1: 2 combos per lane ----
    #pragma unroll
    for (int cc = 0; cc < 2; ++cc) {
        const int c = lane + cc * 64;        // c = h*16 + l*4 + p
        const int l = (c >> 2) & 3;
        const int hh = 64 >> l;
        const int ww = 112 >> l;
        const int s  = (l > 0 ? 7168 : 0) + (l > 1 ? 1792 : 0) + (l > 2 ? 448 : 0);
        const float offx = oa[c * 2 + 0];
        const float offy = oa[c * 2 + 1];
        const float aw   = oa[256 + c];
        const float x = rx * (float)ww - 0.5f + offx;
        const float y = ry * (float)hh - 0.5f + offy;
        const float x0f = floorf(x), y0f = floorf(y);
        const float lx = x - x0f, ly = y - y0f;
        const int x0 = (int)x0f, y0 = (int)y0f;
        const int x1 = x0 + 1,  y1 = y0 + 1;
        const bool vx0 = (x0 >= 0) & (x0 < ww);
        const bool vx1 = (x1 >= 0) & (x1 < ww);
        const bool vy0 = (y0 >= 0) & (y0 < hh);
        const bool vy1 = (y1 >= 0) & (y1 < hh);
        const int xc0 = min(max(x0, 0), ww - 1);
        const int xc1 = min(max(x1, 0), ww - 1);
        const int yc0 = min(max(y0, 0), hh - 1);
        const int yc1 = min(max(y1, 0), hh - 1);
        float w00 = (1.f - ly) * (1.f - lx) * aw;
        float w01 = (1.f - ly) * lx * aw;
        float w10 = ly * (1.f - lx) * aw;
        float w11 = ly * lx * aw;
        w00 = (vy0 & vx0) ? w00 : 0.f;
        w01 = (vy0 & vx1) ? w01 : 0.f;
        w10 = (vy1 & vx0) ? w10 : 0.f;
        w11 = (vy1 & vx1) ? w11 : 0.f;
        sidx[wq][c] = make_int4(s + yc0 * ww + xc0, s + yc0 * ww + xc1,
                                s + yc1 * ww + xc0, s + yc1 * ww + xc1);
        swt[wq][c]  = make_float4(w00, w01, w10, w11);
    }
    __syncthreads();

    // ---- phase 2: gather. lane = h*8 + d4 ----
    const int h  = lane >> 3;
    const int d4 = lane & 7;
    const int laneoff = h * 8 + d4;                 // float4 units within pixel
    const float4* vb4 = (const float4*)(v + (size_t)bn * NV * CDIM);
    float4 acc = make_float4(0.f, 0.f, 0.f, 0.f);
    #pragma unroll 4
    for (int p = 0; p < 16; ++p) {
        const int c = h * 16 + p;
        const int4   id = sidx[wq][c];
        const float4 wt = swt[wq][c];
        const float4 g00 = vb4[(size_t)(id.x * 64 + laneoff)];
        const float4 g01 = vb4[(size_t)(id.y * 64 + laneoff)];
        const float4 g10 = vb4[(size_t)(id.z * 64 + laneoff)];
        const float4 g11 = vb4[(size_t)(id.w * 64 + laneoff)];
        acc.x += wt.x * g00.x + wt.y * g01.x + wt.z * g10.x + wt.w * g11.x;
        acc.y += wt.x * g00.y + wt.y * g01.y + wt.z * g10.y + wt.w * g11.y;
        acc.z += wt.x * g00.z + wt.y * g01.z + wt.z * g10.z + wt.w * g11.z;
        acc.w += wt.x * g00.w + wt.y * g01.w + wt.z * g10.w + wt.w * g11.w;
    }
    *(float4*)(attn_in + (size_t)bq * CDIM + h * 32 + d4 * 4) = acc;
}

// ------------- masked reduce over N: S[b,q,:] = sum_n m_n * attn_in ----------
__global__ __launch_bounds__(256) void reduce_mask_kernel(
    const float* __restrict__ attn_in, const void* __restrict__ maskp,
    const int* __restrict__ flag,
    float* __restrict__ S, float* __restrict__ cnts)
{
    const int bq = blockIdx.x;       // B*Q
    const int b = bq >> 13, q = bq & (QQ - 1);
    const int tid = threadIdx.x;
    __shared__ float sm[4];
    if (tid < 4) {
        const int f = *flag;
        sm[tid] = read_mask(maskp, f, (size_t)(b * 4 + tid) * QQ + q);
    }
    __syncthreads();
    float acc = 0.f;
    #pragma unroll
    for (int n = 0; n < 4; ++n)
        if (sm[n] != 0.f)
            acc += attn_in[(((size_t)(b * 4 + n)) * QQ + q) * CDIM + tid];
    S[(size_t)bq * CDIM + tid] = acc;
    if (tid == 0) cnts[bq] = sm[0] + sm[1] + sm[2] + sm[3];
}

// ------------- final: out = (sm*(q+bo) + T) / max(sm,1) ----------------------
__global__ __launch_bounds__(256) void final_kernel(
    const float* __restrict__ query, const float* __restrict__ T,
    const float* __restrict__ bo, const float* __restrict__ cnts,
    float* __restrict__ out)
{
    const int bq = blockIdx.x;       // B*Q
    const int tid = threadIdx.x;
    const float sm = cnts[bq];
    const float cnt = fmaxf(sm, 1.f);
    const size_t i = (size_t)bq * CDIM + tid;
    out[i] = (sm * (query[i] + bo[tid]) + T[i]) / cnt;
}

extern "C" void kernel_launch(void* const* d_in, const int* in_sizes, int n_in,
                              void* d_out, int out_size, void* d_ws, size_t ws_size,
                              hipStream_t stream)
{
    (void)in_sizes; (void)n_in; (void)out_size; (void)ws_size;
    const float* query = (const float*)d_in[0];   // (B,Z,Y,X,C) = (16384,256)
    const float* value = (const float*)d_in[1];   // (8,9520,256)
    const float* refp  = (const float*)d_in[2];   // (8,8192,2)
    const void*  maskp = d_in[3];                 // (8,8192) bool
    const float* Wv    = (const float*)d_in[6];
    const float* bv    = (const float*)d_in[7];
    const float* Woff  = (const float*)d_in[8];
    const float* boff  = (const float*)d_in[9];
    const float* Watt  = (const float*)d_in[10];
    const float* batt  = (const float*)d_in[11];
    const float* Wo    = (const float*)d_in[12];
    const float* bo    = (const float*)d_in[13];
    float* out = (float*)d_out;
    char* ws = (char*)d_ws;

    // workspace layout (bytes)
    float* v_proj  = (float*)(ws + 0);            // 76160*256*4 = 77,987,840
    float* offatt  = (float*)(ws + 77987840);     // 16384*384*4 = 25,165,824
    float* attn_in = (float*)(ws + 103153664);    // 65536*256*4 = 67,108,864
    float* cnts    = (float*)(ws + 170262528);    // 16384*4
    int*   flag    = (int*)  (ws + 170328064);    // 4

    detect_mask_kernel<<<1, 256, 0, stream>>>((const unsigned int*)maskp, flag);

    // v = value @ Wv + bv   (76160 x 256 x 256)
    gemm_bias_kernel<<<dim3(76160 / BM, CDIM / BNT), 256, 0, stream>>>(
        value, CDIM, Wv, CDIM, bv, v_proj, CDIM, CDIM);

    // offatt[:, :256] = query @ Woff + boff   (16384 x 256 x 256)
    gemm_bias_kernel<<<dim3(16384 / BM, 256 / BNT), 256, 0, stream>>>(
        query, CDIM, Woff, 256, boff, offatt, 384, CDIM);

    // offatt[:, 256:] = query @ Watt + batt   (16384 x 128 x 256)
    gemm_bias_kernel<<<dim3(16384 / BM, 128 / BNT), 256, 0, stream>>>(
        query, CDIM, Watt, 128, batt, offatt + 256, 384, CDIM);

    softmax_kernel<<<512, 256, 0, stream>>>(offatt);

    sample_kernel<<<16384, 256, 0, stream>>>(v_proj, offatt, refp, attn_in);

    // S (reuse offatt region, flat 16384x256) + counts
    reduce_mask_kernel<<<16384, 256, 0, stream>>>(attn_in, maskp, flag, offatt, cnts);

    // T = S @ Wo  (reuse attn_in region, flat 16384x256)
    gemm_bias_kernel<<<dim3(16384 / BM, CDIM / BNT), 256, 0, stream>>>(
        offatt, CDIM, Wo, CDIM, nullptr, attn_in, CDIM, CDIM);

    final_kernel<<<16384, 256, 0, stream>>>(query, attn_in, bo, cnts, out);
}

// Round 3
// 418.333 us; speedup vs baseline: 1.7914x; 1.1017x over previous
//
#include <hip/hip_runtime.h>
#include <hip/hip_bf16.h>
#include <cstdint>
#include <cstddef>

// Problem constants (fixed by setup_inputs)
#define QQ 8192       // Z*Y*X
#define CDIM 256
#define NV 9520
#define NLVL 4
#define NPTS 4
#define NHEAD 8
// levels: (h,w) = (64,112),(32,56),(16,28),(8,14); starts 0,7168,8960,9408

__device__ __forceinline__ unsigned short f2bf(float f)
{
    unsigned u = __float_as_uint(f);
    unsigned r = (u + 0x7fffu + ((u >> 16) & 1u)) >> 16;   // RNE
    return (unsigned short)r;
}

// ---------------- GEMM: C = A(MxK) @ B(KxN) + bias, row-major ----------------
#define BM 64
#define BNT 64
#define BK 16

template <typename OutT>
__global__ __launch_bounds__(256) void gemm_bias_kernel(
    const float* __restrict__ A, int lda,
    const float* __restrict__ B, int ldb,
    const float* __restrict__ bias,
    OutT* __restrict__ C, int ldc, int K)
{
    __shared__ float As[BK][BM];
    __shared__ float Bs[BK][BNT];
    const int tid = threadIdx.x;
    const int tx = tid & 15, ty = tid >> 4;
    const int arow = tid >> 2;          // 0..63
    const int akq  = (tid & 3) << 2;    // 0,4,8,12
    const int brow = tid >> 4;          // 0..15
    const int bcol = (tid & 15) << 2;   // 0..60
    const float* Ab = A + (size_t)blockIdx.x * BM * lda;
    const float* Bb = B + (size_t)blockIdx.y * BNT;
    float acc[4][4] = {};
    for (int kt = 0; kt < K; kt += BK) {
        float4 av = *(const float4*)(Ab + (size_t)arow * lda + kt + akq);
        As[akq + 0][arow] = av.x;
        As[akq + 1][arow] = av.y;
        As[akq + 2][arow] = av.z;
        As[akq + 3][arow] = av.w;
        *(float4*)&Bs[brow][bcol] =
            *(const float4*)(Bb + (size_t)(kt + brow) * ldb + bcol);
        __syncthreads();
        #pragma unroll
        for (int k = 0; k < BK; ++k) {
            float4 a4 = *(const float4*)&As[k][ty << 2];
            float4 b4 = *(const float4*)&Bs[k][tx << 2];
            float a[4] = {a4.x, a4.y, a4.z, a4.w};
            float b[4] = {b4.x, b4.y, b4.z, b4.w};
            #pragma unroll
            for (int i = 0; i < 4; ++i)
                #pragma unroll
                for (int j = 0; j < 4; ++j)
                    acc[i][j] += a[i] * b[j];
        }
        __syncthreads();
    }
    const int row0 = blockIdx.x * BM + (ty << 2);
    const int col0 = blockIdx.y * BNT + (tx << 2);
    float4 bias4 = make_float4(0.f, 0.f, 0.f, 0.f);
    if (bias) bias4 = *(const float4*)(bias + col0);
    #pragma unroll
    for (int i = 0; i < 4; ++i) {
        float r0 = acc[i][0] + bias4.x, r1 = acc[i][1] + bias4.y;
        float r2 = acc[i][2] + bias4.z, r3 = acc[i][3] + bias4.w;
        if constexpr (sizeof(OutT) == 4) {
            float4 o = make_float4(r0, r1, r2, r3);
            *(float4*)((float*)C + (size_t)(row0 + i) * ldc + col0) = o;
        } else {
            ushort4 o;
            o.x = f2bf(r0); o.y = f2bf(r1); o.z = f2bf(r2); o.w = f2bf(r3);
            *(ushort4*)((unsigned short*)C + (size_t)(row0 + i) * ldc + col0) = o;
        }
    }
}

// ---------------- mask dtype sniffer (bool-as-u8 vs i32 vs f32) --------------
// flag: 0 = uint8, 1 = int32(0/1), 2 = float32(0.0/1.0)
__global__ void detect_mask_kernel(const unsigned int* __restrict__ m, int* flag)
{
    __shared__ int notI32, notF32;
    if (threadIdx.x == 0) { notI32 = 0; notF32 = 0; }
    __syncthreads();
    for (int i = threadIdx.x; i < 1024; i += 256) {
        unsigned v = m[i];
        if (v > 1u) notI32 = 1;
        if (v != 0u && v != 0x3F800000u) notF32 = 1;
    }
    __syncthreads();
    if (threadIdx.x == 0) *flag = (!notI32) ? 1 : ((!notF32) ? 2 : 0);
}

__device__ __forceinline__ float read_mask(const void* p, int f, size_t i)
{
    if (f == 1) return (float)((const int*)p)[i];
    if (f == 2) return ((const float*)p)[i];
    return (float)((const unsigned char*)p)[i];
}

// ---------------- softmax over L*P=16 per (b,q,h), in place ------------------
__global__ void softmax_kernel(float* __restrict__ offatt)
{
    int t = blockIdx.x * blockDim.x + threadIdx.x;   // B*Q*H = 131072
    int bq = t >> 3, h = t & 7;
    float* p = offatt + (size_t)bq * 384 + 256 + h * 16;
    float m = -3.4e38f;
    float e[16];
    #pragma unroll
    for (int i = 0; i < 16; ++i) m = fmaxf(m, p[i]);
    float s = 0.f;
    #pragma unroll
    for (int i = 0; i < 16; ++i) { e[i] = __expf(p[i] - m); s += e[i]; }
    float inv = 1.f / s;
    #pragma unroll
    for (int i = 0; i < 16; ++i) p[i] = e[i] * inv;
}

// ---------------- deformable bilinear sampling -------------------------------
// one WAVE per (bn,q); 4 q's per 256-thread block. v is bf16.
// Phase 1: 128 (h,l,p) combos computed once -> LDS {int4 idx, float4 weight},
//          padded [h][17] so per-p reads of 8 h-slots hit distinct banks.
// Phase 2: lane = h*8+d4 gathers uint2 (4 bf16 channels) per corner.
__global__ __launch_bounds__(256) void sample_kernel(
    const unsigned short* __restrict__ v,  // (BN, NV, 256) bf16
    const float* __restrict__ offatt,      // (B*Q, 384): 256 off + 128 aw
    const float* __restrict__ refp,        // (BN, Q, 2)
    float* __restrict__ attn_in)           // (BN, Q, 256) f32
{
    __shared__ int4   sidx[4][NHEAD][17];
    __shared__ float4 swt[4][NHEAD][17];
    const int tid  = threadIdx.x;
    const int wq   = tid >> 6;           // wave id 0..3
    const int lane = tid & 63;
    const int bq   = blockIdx.x * 4 + wq;    // BN*Q index
    const int bn   = bq >> 13;
    const int q    = bq & (QQ - 1);
    const int b    = bn >> 2;

    const float* oa = offatt + ((size_t)(b * QQ + q)) * 384;
    const float rx = refp[((size_t)bn * QQ + q) * 2 + 0];
    const float ry = refp[((size_t)bn * QQ + q) * 2 + 1];

    // ---- phase 1: 2 combos per lane ----
    #pragma unroll
    for (int cc = 0; cc < 2; ++cc) {
        const int c = lane + cc * 64;        // c = h*16 + l*4 + p
        const int hcomb = c >> 4;
        const int pcomb = c & 15;
        const int l = (c >> 2) & 3;
        const int hh = 64 >> l;
        const int ww = 112 >> l;
        const int s  = (l > 0 ? 7168 : 0) + (l > 1 ? 1792 : 0) + (l > 2 ? 448 : 0);
        const float offx = oa[c * 2 + 0];
        const float offy = oa[c * 2 + 1];
        const float aw   = oa[256 + c];
        const float x = rx * (float)ww - 0.5f + offx;
        const float y = ry * (float)hh - 0.5f + offy;
        const float x0f = floorf(x), y0f = floorf(y);
        const float lx = x - x0f, ly = y - y0f;
        const int x0 = (int)x0f, y0 = (int)y0f;
        const int x1 = x0 + 1,  y1 = y0 + 1;
        const bool vx0 = (x0 >= 0) & (x0 < ww);
        const bool vx1 = (x1 >= 0) & (x1 < ww);
        const bool vy0 = (y0 >= 0) & (y0 < hh);
        const bool vy1 = (y1 >= 0) & (y1 < hh);
        const int xc0 = min(max(x0, 0), ww - 1);
        const int xc1 = min(max(x1, 0), ww - 1);
        const int yc0 = min(max(y0, 0), hh - 1);
        const int yc1 = min(max(y1, 0), hh - 1);
        float w00 = (1.f - ly) * (1.f - lx) * aw;
        float w01 = (1.f - ly) * lx * aw;
        float w10 = ly * (1.f - lx) * aw;
        float w11 = ly * lx * aw;
        w00 = (vy0 & vx0) ? w00 : 0.f;
        w01 = (vy0 & vx1) ? w01 : 0.f;
        w10 = (vy1 & vx0) ? w10 : 0.f;
        w11 = (vy1 & vx1) ? w11 : 0.f;
        sidx[wq][hcomb][pcomb] = make_int4(s + yc0 * ww + xc0, s + yc0 * ww + xc1,
                                           s + yc1 * ww + xc0, s + yc1 * ww + xc1);
        swt[wq][hcomb][pcomb]  = make_float4(w00, w01, w10, w11);
    }
    __syncthreads();

    // ---- phase 2: gather. lane = h*8 + d4, 4 bf16 channels per lane ----
    const int h  = lane >> 3;
    const int d4 = lane & 7;
    const int laneoff = h * 8 + d4;   // uint2 units within pixel (64 per pixel)
    const uint2* vb = (const uint2*)(v + (size_t)bn * NV * CDIM);
    float4 acc = make_float4(0.f, 0.f, 0.f, 0.f);
    #pragma unroll 4
    for (int p = 0; p < 16; ++p) {
        const int4   id = sidx[wq][h][p];
        const float4 wt = swt[wq][h][p];
        const uint2 g00 = vb[(size_t)(id.x * 64 + laneoff)];
        const uint2 g01 = vb[(size_t)(id.y * 64 + laneoff)];
        const uint2 g10 = vb[(size_t)(id.z * 64 + laneoff)];
        const uint2 g11 = vb[(size_t)(id.w * 64 + laneoff)];
        #define BFLO(u) __uint_as_float((u) << 16)
        #define BFHI(u) __uint_as_float((u) & 0xffff0000u)
        acc.x += wt.x * BFLO(g00.x) + wt.y * BFLO(g01.x) + wt.z * BFLO(g10.x) + wt.w * BFLO(g11.x);
        acc.y += wt.x * BFHI(g00.x) + wt.y * BFHI(g01.x) + wt.z * BFHI(g10.x) + wt.w * BFHI(g11.x);
        acc.z += wt.x * BFLO(g00.y) + wt.y * BFLO(g01.y) + wt.z * BFLO(g10.y) + wt.w * BFLO(g11.y);
        acc.w += wt.x * BFHI(g00.y) + wt.y * BFHI(g01.y) + wt.z * BFHI(g10.y) + wt.w * BFHI(g11.y);
        #undef BFLO
        #undef BFHI
    }
    *(float4*)(attn_in + (size_t)bq * CDIM + h * 32 + d4 * 4) = acc;
}

// ------------- masked reduce over N: S[b,q,:] = sum_n m_n * attn_in ----------
__global__ __launch_bounds__(256) void reduce_mask_kernel(
    const float* __restrict__ attn_in, const void* __restrict__ maskp,
    const int* __restrict__ flag,
    float* __restrict__ S, float* __restrict__ cnts)
{
    const int bq = blockIdx.x;       // B*Q
    const int b = bq >> 13, q = bq & (QQ - 1);
    const int tid = threadIdx.x;
    __shared__ float sm[4];
    if (tid < 4) {
        const int f = *flag;
        sm[tid] = read_mask(maskp, f, (size_t)(b * 4 + tid) * QQ + q);
    }
    __syncthreads();
    float acc = 0.f;
    #pragma unroll
    for (int n = 0; n < 4; ++n)
        if (sm[n] != 0.f)
            acc += attn_in[(((size_t)(b * 4 + n)) * QQ + q) * CDIM + tid];
    S[(size_t)bq * CDIM + tid] = acc;
    if (tid == 0) cnts[bq] = sm[0] + sm[1] + sm[2] + sm[3];
}

// ------------- final: out = (sm*(q+bo) + T) / max(sm,1) ----------------------
__global__ __launch_bounds__(256) void final_kernel(
    const float* __restrict__ query, const float* __restrict__ T,
    const float* __restrict__ bo, const float* __restrict__ cnts,
    float* __restrict__ out)
{
    const int bq = blockIdx.x;       // B*Q
    const int tid = threadIdx.x;
    const float sm = cnts[bq];
    const float cnt = fmaxf(sm, 1.f);
    const size_t i = (size_t)bq * CDIM + tid;
    out[i] = (sm * (query[i] + bo[tid]) + T[i]) / cnt;
}

extern "C" void kernel_launch(void* const* d_in, const int* in_sizes, int n_in,
                              void* d_out, int out_size, void* d_ws, size_t ws_size,
                              hipStream_t stream)
{
    (void)in_sizes; (void)n_in; (void)out_size; (void)ws_size;
    const float* query = (const float*)d_in[0];   // (B,Z,Y,X,C) = (16384,256)
    const float* value = (const float*)d_in[1];   // (8,9520,256)
    const float* refp  = (const float*)d_in[2];   // (8,8192,2)
    const void*  maskp = d_in[3];                 // (8,8192) bool
    const float* Wv    = (const float*)d_in[6];
    const float* bv    = (const float*)d_in[7];
    const float* Woff  = (const float*)d_in[8];
    const float* boff  = (const float*)d_in[9];
    const float* Watt  = (const float*)d_in[10];
    const float* batt  = (const float*)d_in[11];
    const float* Wo    = (const float*)d_in[12];
    const float* bo    = (const float*)d_in[13];
    float* out = (float*)d_out;
    char* ws = (char*)d_ws;

    // workspace layout (bytes)
    unsigned short* v_proj = (unsigned short*)(ws + 0);  // 76160*256*2 = 38,993,920
    float* offatt  = (float*)(ws + 38993920);     // 16384*384*4 = 25,165,824
    float* attn_in = (float*)(ws + 64159744);     // 65536*256*4 = 67,108,864
    float* cnts    = (float*)(ws + 131268608);    // 16384*4 = 65,536
    int*   flag    = (int*)  (ws + 131334144);    // 4

    detect_mask_kernel<<<1, 256, 0, stream>>>((const unsigned int*)maskp, flag);

    // v = value @ Wv + bv   (76160 x 256 x 256) -> bf16
    gemm_bias_kernel<unsigned short><<<dim3(76160 / BM, CDIM / BNT), 256, 0, stream>>>(
        value, CDIM, Wv, CDIM, bv, v_proj, CDIM, CDIM);

    // offatt[:, :256] = query @ Woff + boff   (16384 x 256 x 256)
    gemm_bias_kernel<float><<<dim3(16384 / BM, 256 / BNT), 256, 0, stream>>>(
        query, CDIM, Woff, 256, boff, offatt, 384, CDIM);

    // offatt[:, 256:] = query @ Watt + batt   (16384 x 128 x 256)
    gemm_bias_kernel<float><<<dim3(16384 / BM, 128 / BNT), 256, 0, stream>>>(
        query, CDIM, Watt, 128, batt, offatt + 256, 384, CDIM);

    softmax_kernel<<<512, 256, 0, stream>>>(offatt);

    sample_kernel<<<16384, 256, 0, stream>>>(v_proj, offatt, refp, attn_in);

    // S (reuse offatt region, flat 16384x256) + counts
    reduce_mask_kernel<<<16384, 256, 0, stream>>>(attn_in, maskp, flag, offatt, cnts);

    // T = S @ Wo  (reuse attn_in region, flat 16384x256)
    gemm_bias_kernel<float><<<dim3(16384 / BM, CDIM / BNT), 256, 0, stream>>>(
        offatt, CDIM, Wo, CDIM, nullptr, attn_in, CDIM, CDIM);

    final_kernel<<<16384, 256, 0, stream>>>(query, attn_in, bo, cnts, out);
}

// Round 4
// 349.519 us; speedup vs baseline: 2.1441x; 1.1969x over previous
//
#include <hip/hip_runtime.h>
#include <hip/hip_bf16.h>
#include <cstdint>
#include <cstddef>

// Problem constants (fixed by setup_inputs)
#define QQ 8192       // Z*Y*X
#define CDIM 256
#define NV 9520
#define NLVL 4
#define NPTS 4
#define NHEAD 8
// levels: (h,w) = (64,112),(32,56),(16,28),(8,14); starts 0,7168,8960,9408

__device__ __forceinline__ unsigned short f2bf(float f)
{
    unsigned u = __float_as_uint(f);
    unsigned r = (u + 0x7fffu + ((u >> 16) & 1u)) >> 16;   // RNE
    return (unsigned short)r;
}

// ---------------- GEMM: C = A(MxK) @ B(KxN) + bias, row-major ----------------
#define BM 64
#define BNT 64
#define BK 16

template <typename OutT>
__global__ __launch_bounds__(256) void gemm_bias_kernel(
    const float* __restrict__ A, int lda,
    const float* __restrict__ B, int ldb,
    const float* __restrict__ bias,
    OutT* __restrict__ C, int ldc, int K)
{
    __shared__ float As[BK][BM];
    __shared__ float Bs[BK][BNT];
    const int tid = threadIdx.x;
    const int tx = tid & 15, ty = tid >> 4;
    const int arow = tid >> 2;          // 0..63
    const int akq  = (tid & 3) << 2;    // 0,4,8,12
    const int brow = tid >> 4;          // 0..15
    const int bcol = (tid & 15) << 2;   // 0..60
    const float* Ab = A + (size_t)blockIdx.x * BM * lda;
    const float* Bb = B + (size_t)blockIdx.y * BNT;
    float acc[4][4] = {};
    for (int kt = 0; kt < K; kt += BK) {
        float4 av = *(const float4*)(Ab + (size_t)arow * lda + kt + akq);
        As[akq + 0][arow] = av.x;
        As[akq + 1][arow] = av.y;
        As[akq + 2][arow] = av.z;
        As[akq + 3][arow] = av.w;
        *(float4*)&Bs[brow][bcol] =
            *(const float4*)(Bb + (size_t)(kt + brow) * ldb + bcol);
        __syncthreads();
        #pragma unroll
        for (int k = 0; k < BK; ++k) {
            float4 a4 = *(const float4*)&As[k][ty << 2];
            float4 b4 = *(const float4*)&Bs[k][tx << 2];
            float a[4] = {a4.x, a4.y, a4.z, a4.w};
            float b[4] = {b4.x, b4.y, b4.z, b4.w};
            #pragma unroll
            for (int i = 0; i < 4; ++i)
                #pragma unroll
                for (int j = 0; j < 4; ++j)
                    acc[i][j] += a[i] * b[j];
        }
        __syncthreads();
    }
    const int row0 = blockIdx.x * BM + (ty << 2);
    const int col0 = blockIdx.y * BNT + (tx << 2);
    float4 bias4 = make_float4(0.f, 0.f, 0.f, 0.f);
    if (bias) bias4 = *(const float4*)(bias + col0);
    #pragma unroll
    for (int i = 0; i < 4; ++i) {
        float r0 = acc[i][0] + bias4.x, r1 = acc[i][1] + bias4.y;
        float r2 = acc[i][2] + bias4.z, r3 = acc[i][3] + bias4.w;
        if constexpr (sizeof(OutT) == 4) {
            float4 o = make_float4(r0, r1, r2, r3);
            *(float4*)((float*)C + (size_t)(row0 + i) * ldc + col0) = o;
        } else {
            ushort4 o;
            o.x = f2bf(r0); o.y = f2bf(r1); o.z = f2bf(r2); o.w = f2bf(r3);
            *(ushort4*)((unsigned short*)C + (size_t)(row0 + i) * ldc + col0) = o;
        }
    }
}

// ------- GEMM fused with final residual/mask epilogue: out = (sm*(q+bo)+A@B)/max(sm,1)
__global__ __launch_bounds__(256) void gemm_wo_final_kernel(
    const float* __restrict__ A,        // S (B*Q, 256)
    const float* __restrict__ B,        // Wo (256,256)
    const float* __restrict__ query,    // (B*Q, 256)
    const float* __restrict__ bo,       // (256)
    const float* __restrict__ cnts,     // (B*Q)
    float* __restrict__ C)              // out (B*Q, 256)
{
    __shared__ float As[BK][BM];
    __shared__ float Bs[BK][BNT];
    const int tid = threadIdx.x;
    const int tx = tid & 15, ty = tid >> 4;
    const int arow = tid >> 2;
    const int akq  = (tid & 3) << 2;
    const int brow = tid >> 4;
    const int bcol = (tid & 15) << 2;
    const float* Ab = A + (size_t)blockIdx.x * BM * CDIM;
    const float* Bb = B + (size_t)blockIdx.y * BNT;
    float acc[4][4] = {};
    for (int kt = 0; kt < CDIM; kt += BK) {
        float4 av = *(const float4*)(Ab + (size_t)arow * CDIM + kt + akq);
        As[akq + 0][arow] = av.x;
        As[akq + 1][arow] = av.y;
        As[akq + 2][arow] = av.z;
        As[akq + 3][arow] = av.w;
        *(float4*)&Bs[brow][bcol] =
            *(const float4*)(Bb + (size_t)(kt + brow) * CDIM + bcol);
        __syncthreads();
        #pragma unroll
        for (int k = 0; k < BK; ++k) {
            float4 a4 = *(const float4*)&As[k][ty << 2];
            float4 b4 = *(const float4*)&Bs[k][tx << 2];
            float a[4] = {a4.x, a4.y, a4.z, a4.w};
            float b[4] = {b4.x, b4.y, b4.z, b4.w};
            #pragma unroll
            for (int i = 0; i < 4; ++i)
                #pragma unroll
                for (int j = 0; j < 4; ++j)
                    acc[i][j] += a[i] * b[j];
        }
        __syncthreads();
    }
    const int row0 = blockIdx.x * BM + (ty << 2);
    const int col0 = blockIdx.y * BNT + (tx << 2);
    const float4 bov = *(const float4*)(bo + col0);
    #pragma unroll
    for (int i = 0; i < 4; ++i) {
        const int row = row0 + i;
        const float sm = cnts[row];
        const float inv = 1.f / fmaxf(sm, 1.f);
        const float4 qv = *(const float4*)(query + (size_t)row * CDIM + col0);
        float4 o;
        o.x = (sm * (qv.x + bov.x) + acc[i][0]) * inv;
        o.y = (sm * (qv.y + bov.y) + acc[i][1]) * inv;
        o.z = (sm * (qv.z + bov.z) + acc[i][2]) * inv;
        o.w = (sm * (qv.w + bov.w) + acc[i][3]) * inv;
        *(float4*)(C + (size_t)row * CDIM + col0) = o;
    }
}

// ---------------- mask dtype sniffer (bool-as-u8 vs i32 vs f32) --------------
// flag: 0 = uint8, 1 = int32(0/1), 2 = float32(0.0/1.0)
__global__ void detect_mask_kernel(const unsigned int* __restrict__ m, int* flag)
{
    __shared__ int notI32, notF32;
    if (threadIdx.x == 0) { notI32 = 0; notF32 = 0; }
    __syncthreads();
    for (int i = threadIdx.x; i < 1024; i += 256) {
        unsigned v = m[i];
        if (v > 1u) notI32 = 1;
        if (v != 0u && v != 0x3F800000u) notF32 = 1;
    }
    __syncthreads();
    if (threadIdx.x == 0) *flag = (!notI32) ? 1 : ((!notF32) ? 2 : 0);
}

__device__ __forceinline__ float read_mask(const void* p, int f, size_t i)
{
    if (f == 1) return (float)((const int*)p)[i];
    if (f == 2) return ((const float*)p)[i];
    return (float)((const unsigned char*)p)[i];
}

// ---------------- softmax over L*P=16 per (b,q,h), in place ------------------
__global__ void softmax_kernel(float* __restrict__ offatt)
{
    int t = blockIdx.x * blockDim.x + threadIdx.x;   // B*Q*H = 131072
    int bq = t >> 3, h = t & 7;
    float* p = offatt + (size_t)bq * 384 + 256 + h * 16;
    float m = -3.4e38f;
    float e[16];
    #pragma unroll
    for (int i = 0; i < 16; ++i) m = fmaxf(m, p[i]);
    float s = 0.f;
    #pragma unroll
    for (int i = 0; i < 16; ++i) { e[i] = __expf(p[i] - m); s += e[i]; }
    float inv = 1.f / s;
    #pragma unroll
    for (int i = 0; i < 16; ++i) p[i] = e[i] * inv;
}

// -------- fused deformable sampling + masked reduce over N -------------------
// One block per (b,q); wave n (0..3) handles view bn = b*4+n.
// Masked-out waves (m_n==0) skip the gather phase entirely.
// Phase 1 (all waves): 128 (h,l,p) combos -> LDS {int4 idx, float4 weight}.
// Phase 2 (live waves): lane = h*8+d4 gathers uint2 (4 bf16 ch) per corner.
// Reduce: LDS cross-wave sum -> S[b,q,:], counts -> cnts[b,q].
__global__ __launch_bounds__(256) void sample_reduce_kernel(
    const unsigned short* __restrict__ v,  // (BN, NV, 256) bf16
    const float* __restrict__ offatt,      // (B*Q, 384): 256 off + 128 aw
    const float* __restrict__ refp,        // (BN, Q, 2)
    const void* __restrict__ maskp,        // (BN, Q) bool
    const int* __restrict__ flag,
    float* __restrict__ S,                 // (B*Q, 256) f32
    float* __restrict__ cnts)              // (B*Q)
{
    __shared__ int4   sidx[4][NHEAD][17];
    __shared__ float4 swt[4][NHEAD][17];
    __shared__ float  red[4][CDIM];
    __shared__ float  smv[4];
    const int tid  = threadIdx.x;
    const int wn   = tid >> 6;           // wave id = view n
    const int lane = tid & 63;
    const int bq   = blockIdx.x;         // B*Q index
    const int b    = bq >> 13;
    const int q    = bq & (QQ - 1);
    const int bn   = b * 4 + wn;

    const float mn = read_mask(maskp, *flag, (size_t)bn * QQ + q);
    if (lane == 0) smv[wn] = mn;

    const float* oa = offatt + (size_t)bq * 384;
    const float rx = refp[((size_t)bn * QQ + q) * 2 + 0];
    const float ry = refp[((size_t)bn * QQ + q) * 2 + 1];

    // ---- phase 1 (unconditional): 2 combos per lane ----
    #pragma unroll
    for (int cc = 0; cc < 2; ++cc) {
        const int c = lane + cc * 64;        // c = h*16 + l*4 + p
        const int hcomb = c >> 4;
        const int pcomb = c & 15;
        const int l = (c >> 2) & 3;
        const int hh = 64 >> l;
        const int ww = 112 >> l;
        const int s  = (l > 0 ? 7168 : 0) + (l > 1 ? 1792 : 0) + (l > 2 ? 448 : 0);
        const float offx = oa[c * 2 + 0];
        const float offy = oa[c * 2 + 1];
        const float aw   = oa[256 + c];
        const float x = rx * (float)ww - 0.5f + offx;
        const float y = ry * (float)hh - 0.5f + offy;
        const float x0f = floorf(x), y0f = floorf(y);
        const float lx = x - x0f, ly = y - y0f;
        const int x0 = (int)x0f, y0 = (int)y0f;
        const int x1 = x0 + 1,  y1 = y0 + 1;
        const bool vx0 = (x0 >= 0) & (x0 < ww);
        const bool vx1 = (x1 >= 0) & (x1 < ww);
        const bool vy0 = (y0 >= 0) & (y0 < hh);
        const bool vy1 = (y1 >= 0) & (y1 < hh);
        const int xc0 = min(max(x0, 0), ww - 1);
        const int xc1 = min(max(x1, 0), ww - 1);
        const int yc0 = min(max(y0, 0), hh - 1);
        const int yc1 = min(max(y1, 0), hh - 1);
        float w00 = (1.f - ly) * (1.f - lx) * aw;
        float w01 = (1.f - ly) * lx * aw;
        float w10 = ly * (1.f - lx) * aw;
        float w11 = ly * lx * aw;
        w00 = (vy0 & vx0) ? w00 : 0.f;
        w01 = (vy0 & vx1) ? w01 : 0.f;
        w10 = (vy1 & vx0) ? w10 : 0.f;
        w11 = (vy1 & vx1) ? w11 : 0.f;
        sidx[wn][hcomb][pcomb] = make_int4(s + yc0 * ww + xc0, s + yc0 * ww + xc1,
                                           s + yc1 * ww + xc0, s + yc1 * ww + xc1);
        swt[wn][hcomb][pcomb]  = make_float4(w00, w01, w10, w11);
    }
    __syncthreads();

    // ---- phase 2 (live waves only): gather. lane = h*8 + d4 ----
    float4 acc = make_float4(0.f, 0.f, 0.f, 0.f);
    if (mn != 0.f) {
        const int h  = lane >> 3;
        const int d4 = lane & 7;
        const int laneoff = h * 8 + d4;  // uint2 units within pixel
        const uint2* vb = (const uint2*)(v + (size_t)bn * NV * CDIM);
        #pragma unroll 4
        for (int p = 0; p < 16; ++p) {
            const int4   id = sidx[wn][h][p];
            const float4 wt = swt[wn][h][p];
            const uint2 g00 = vb[(size_t)(id.x * 64 + laneoff)];
            const uint2 g01 = vb[(size_t)(id.y * 64 + laneoff)];
            const uint2 g10 = vb[(size_t)(id.z * 64 + laneoff)];
            const uint2 g11 = vb[(size_t)(id.w * 64 + laneoff)];
            #define BFLO(u) __uint_as_float((u) << 16)
            #define BFHI(u) __uint_as_float((u) & 0xffff0000u)
            acc.x += wt.x * BFLO(g00.x) + wt.y * BFLO(g01.x) + wt.z * BFLO(g10.x) + wt.w * BFLO(g11.x);
            acc.y += wt.x * BFHI(g00.x) + wt.y * BFHI(g01.x) + wt.z * BFHI(g10.x) + wt.w * BFHI(g11.x);
            acc.z += wt.x * BFLO(g00.y) + wt.y * BFLO(g01.y) + wt.z * BFLO(g10.y) + wt.w * BFLO(g11.y);
            acc.w += wt.x * BFHI(g00.y) + wt.y * BFHI(g01.y) + wt.z * BFHI(g10.y) + wt.w * BFHI(g11.y);
            #undef BFLO
            #undef BFHI
        }
    }
    // lane covers output channels [lane*4, lane*4+4)
    *(float4*)&red[wn][lane * 4] = acc;
    __syncthreads();

    // ---- cross-wave masked sum ----
    const float ssum = red[0][tid] + red[1][tid] + red[2][tid] + red[3][tid];
    S[(size_t)bq * CDIM + tid] = ssum;
    if (tid == 0) cnts[bq] = smv[0] + smv[1] + smv[2] + smv[3];
}

extern "C" void kernel_launch(void* const* d_in, const int* in_sizes, int n_in,
                              void* d_out, int out_size, void* d_ws, size_t ws_size,
                              hipStream_t stream)
{
    (void)in_sizes; (void)n_in; (void)out_size; (void)ws_size;
    const float* query = (const float*)d_in[0];   // (B,Z,Y,X,C) = (16384,256)
    const float* value = (const float*)d_in[1];   // (8,9520,256)
    const float* refp  = (const float*)d_in[2];   // (8,8192,2)
    const void*  maskp = d_in[3];                 // (8,8192) bool
    const float* Wv    = (const float*)d_in[6];
    const float* bv    = (const float*)d_in[7];
    const float* Woff  = (const float*)d_in[8];
    const float* boff  = (const float*)d_in[9];
    const float* Watt  = (const float*)d_in[10];
    const float* batt  = (const float*)d_in[11];
    const float* Wo    = (const float*)d_in[12];
    const float* bo    = (const float*)d_in[13];
    float* out = (float*)d_out;
    char* ws = (char*)d_ws;

    // workspace layout (bytes)
    unsigned short* v_proj = (unsigned short*)(ws + 0);  // 76160*256*2 = 38,993,920
    float* offatt  = (float*)(ws + 38993920);     // 16384*384*4 = 25,165,824
    float* S       = (float*)(ws + 64159744);     // 16384*256*4 = 16,777,216
    float* cnts    = (float*)(ws + 80936960);     // 16384*4 = 65,536
    int*   flag    = (int*)  (ws + 81002496);     // 4

    detect_mask_kernel<<<1, 256, 0, stream>>>((const unsigned int*)maskp, flag);

    // v = value @ Wv + bv   (76160 x 256 x 256) -> bf16
    gemm_bias_kernel<unsigned short><<<dim3(76160 / BM, CDIM / BNT), 256, 0, stream>>>(
        value, CDIM, Wv, CDIM, bv, v_proj, CDIM, CDIM);

    // offatt[:, :256] = query @ Woff + boff   (16384 x 256 x 256)
    gemm_bias_kernel<float><<<dim3(16384 / BM, 256 / BNT), 256, 0, stream>>>(
        query, CDIM, Woff, 256, boff, offatt, 384, CDIM);

    // offatt[:, 256:] = query @ Watt + batt   (16384 x 128 x 256)
    gemm_bias_kernel<float><<<dim3(16384 / BM, 128 / BNT), 256, 0, stream>>>(
        query, CDIM, Watt, 128, batt, offatt + 256, 384, CDIM);

    softmax_kernel<<<512, 256, 0, stream>>>(offatt);

    // fused sampling + masked reduce over views
    sample_reduce_kernel<<<16384, 256, 0, stream>>>(
        v_proj, offatt, refp, maskp, flag, S, cnts);

    // out = (sm*(query+bo) + S@Wo) / max(sm,1)
    gemm_wo_final_kernel<<<dim3(16384 / BM, CDIM / BNT), 256, 0, stream>>>(
        S, Wo, query, bo, cnts, out);
}

// Round 5
// 253.853 us; speedup vs baseline: 2.9521x; 1.3769x over previous
//
#include <hip/hip_runtime.h>
#include <cstdint>
#include <cstddef>

// Problem constants (fixed by setup_inputs)
#define QQ 8192       // Z*Y*X
#define CDIM 256
#define NV 9520
#define NLVL 4
#define NPTS 4
#define NHEAD 8
// levels: (h,w) = (64,112),(32,56),(16,28),(8,14); starts 0,7168,8960,9408

typedef __attribute__((ext_vector_type(8))) short short8;
typedef __attribute__((ext_vector_type(4))) float f32x4;

__device__ __forceinline__ unsigned short f2bf(float f)
{
    unsigned u = __float_as_uint(f);
    unsigned r = (u + 0x7fffu + ((u >> 16) & 1u)) >> 16;   // RNE
    return (unsigned short)r;
}

// ---------------- fp32 -> bf16 pack (vectorized) -----------------------------
__global__ __launch_bounds__(256) void pack_bf16_kernel(
    const float4* __restrict__ in, ushort4* __restrict__ out, int n4)
{
    for (int i = blockIdx.x * 256 + threadIdx.x; i < n4; i += gridDim.x * 256) {
        float4 v = in[i];
        ushort4 o;
        o.x = f2bf(v.x); o.y = f2bf(v.y); o.z = f2bf(v.z); o.w = f2bf(v.w);
        out[i] = o;
    }
}

// ---- W (256 rows x ncols) -> Wt (ncols rows x 256) bf16; optional bias copy -
__global__ void pack_wt_kernel(const float* __restrict__ W, int ncols,
                               const float* __restrict__ b,
                               unsigned short* __restrict__ Wt,
                               float* __restrict__ biasOut)
{
    const int n = blockIdx.x, k = threadIdx.x;   // 256 threads = k
    Wt[n * 256 + k] = f2bf(W[(size_t)k * ncols + n]);
    if (k == 0 && biasOut) biasOut[n] = b[n];
}

// ---------------- MFMA bf16 GEMM: C = A(Mx256) @ Bt^T + epilogue -------------
// A: (M,256) bf16 row-major.  Bt: (N,256) bf16 row-major (transposed weights).
// Tile 128x128, 4 waves (2x2), wave tile 64x64 = 4x4 frags of 16x16x32.
// LDS: As/Bs 128 rows x 64 bf16 (128B rows), 16B-block XOR swizzle kb^(row&7).
enum { EP_BIAS_BF16 = 0, EP_BIAS_F32 = 1, EP_WO_FINAL = 2 };

template <int EP>
__global__ __launch_bounds__(256) void mfma_gemm_kernel(
    const unsigned short* __restrict__ A,
    const unsigned short* __restrict__ Bt,
    const float* __restrict__ bias,
    void* __restrict__ C, int ldc,
    const float* __restrict__ query,
    const float* __restrict__ bo,
    const float* __restrict__ cnts)
{
    __shared__ unsigned short As[128 * 64];
    __shared__ unsigned short Bs[128 * 64];
    const int tid  = threadIdx.x;
    const int lane = tid & 63;
    const int wave = tid >> 6;
    const int wm = wave >> 1, wn = wave & 1;
    const int lr = lane & 15, g = lane >> 4;      // g in 0..3
    const int m0 = blockIdx.x * 128, n0 = blockIdx.y * 128;

    f32x4 acc[4][4];
    #pragma unroll
    for (int mi = 0; mi < 4; ++mi)
        #pragma unroll
        for (int ni = 0; ni < 4; ++ni)
            acc[mi][ni] = (f32x4){0.f, 0.f, 0.f, 0.f};

    const unsigned short* gA = A  + (size_t)m0 * 256;
    const unsigned short* gB = Bt + (size_t)n0 * 256;

    for (int kt = 0; kt < 4; ++kt) {              // K = 256 = 4 x 64
        uint4 ra[4], rb[4];
        #pragma unroll
        for (int it = 0; it < 4; ++it) {
            const int fb  = it * 256 + tid;       // 1024 16B-blocks per tile
            const int row = fb >> 3, kb = fb & 7;
            ra[it] = *(const uint4*)(gA + (size_t)row * 256 + kt * 64 + kb * 8);
            rb[it] = *(const uint4*)(gB + (size_t)row * 256 + kt * 64 + kb * 8);
        }
        __syncthreads();   // previous tile's LDS reads drained
        #pragma unroll
        for (int it = 0; it < 4; ++it) {
            const int fb  = it * 256 + tid;
            const int row = fb >> 3, kb = fb & 7;
            const int sw  = (kb ^ (row & 7)) << 3;   // ushort units (16B blocks)
            *(uint4*)&As[row * 64 + sw] = ra[it];
            *(uint4*)&Bs[row * 64 + sw] = rb[it];
        }
        __syncthreads();
        #pragma unroll
        for (int kk = 0; kk < 2; ++kk) {
            const int kb = kk * 4 + g;
            short8 af[4], bf[4];
            #pragma unroll
            for (int mi = 0; mi < 4; ++mi) {
                const int row = wm * 64 + mi * 16 + lr;
                af[mi] = *(const short8*)&As[row * 64 + ((kb ^ (row & 7)) << 3)];
            }
            #pragma unroll
            for (int ni = 0; ni < 4; ++ni) {
                const int row = wn * 64 + ni * 16 + lr;
                bf[ni] = *(const short8*)&Bs[row * 64 + ((kb ^ (row & 7)) << 3)];
            }
            #pragma unroll
            for (int mi = 0; mi < 4; ++mi)
                #pragma unroll
                for (int ni = 0; ni < 4; ++ni)
                    acc[mi][ni] = __builtin_amdgcn_mfma_f32_16x16x32_bf16(
                        af[mi], bf[ni], acc[mi][ni], 0, 0, 0);
        }
    }

    // ---- epilogue.  C/D layout: col = lane&15, row = (lane>>4)*4 + reg ----
    if constexpr (EP == EP_BIAS_BF16 || EP == EP_BIAS_F32) {
        float bcol[4];
        #pragma unroll
        for (int ni = 0; ni < 4; ++ni)
            bcol[ni] = bias[n0 + wn * 64 + ni * 16 + lr];
        #pragma unroll
        for (int mi = 0; mi < 4; ++mi) {
            #pragma unroll
            for (int j = 0; j < 4; ++j) {
                const int gm = m0 + wm * 64 + mi * 16 + g * 4 + j;
                #pragma unroll
                for (int ni = 0; ni < 4; ++ni) {
                    const int gn = n0 + wn * 64 + ni * 16 + lr;
                    const float r = acc[mi][ni][j] + bcol[ni];
                    if constexpr (EP == EP_BIAS_BF16)
                        ((unsigned short*)C)[(size_t)gm * ldc + gn] = f2bf(r);
                    else
                        ((float*)C)[(size_t)gm * ldc + gn] = r;
                }
            }
        }
    } else {   // EP_WO_FINAL: out = (sm*(query+bo) + acc) / max(sm,1)
        float bcol[4];
        #pragma unroll
        for (int ni = 0; ni < 4; ++ni)
            bcol[ni] = bo[n0 + wn * 64 + ni * 16 + lr];
        #pragma unroll
        for (int mi = 0; mi < 4; ++mi) {
            #pragma unroll
            for (int j = 0; j < 4; ++j) {
                const int gm = m0 + wm * 64 + mi * 16 + g * 4 + j;
                const float sm = cnts[gm];
                const float inv = 1.f / fmaxf(sm, 1.f);
                #pragma unroll
                for (int ni = 0; ni < 4; ++ni) {
                    const int gn = n0 + wn * 64 + ni * 16 + lr;
                    const float qv = query[(size_t)gm * CDIM + gn] + bcol[ni];
                    ((float*)C)[(size_t)gm * ldc + gn] =
                        (sm * qv + acc[mi][ni][j]) * inv;
                }
            }
        }
    }
}

// ---------------- mask dtype sniffer (bool-as-u8 vs i32 vs f32) --------------
__global__ void detect_mask_kernel(const unsigned int* __restrict__ m, int* flag)
{
    __shared__ int notI32, notF32;
    if (threadIdx.x == 0) { notI32 = 0; notF32 = 0; }
    __syncthreads();
    for (int i = threadIdx.x; i < 1024; i += 256) {
        unsigned v = m[i];
        if (v > 1u) notI32 = 1;
        if (v != 0u && v != 0x3F800000u) notF32 = 1;
    }
    __syncthreads();
    if (threadIdx.x == 0) *flag = (!notI32) ? 1 : ((!notF32) ? 2 : 0);
}

__device__ __forceinline__ float read_mask(const void* p, int f, size_t i)
{
    if (f == 1) return (float)((const int*)p)[i];
    if (f == 2) return ((const float*)p)[i];
    return (float)((const unsigned char*)p)[i];
}

// ---------------- softmax over L*P=16 per (b,q,h), in place ------------------
__global__ void softmax_kernel(float* __restrict__ offatt)
{
    int t = blockIdx.x * blockDim.x + threadIdx.x;   // B*Q*H = 131072
    int bq = t >> 3, h = t & 7;
    float* p = offatt + (size_t)bq * 384 + 256 + h * 16;
    float m = -3.4e38f;
    float e[16];
    #pragma unroll
    for (int i = 0; i < 16; ++i) m = fmaxf(m, p[i]);
    float s = 0.f;
    #pragma unroll
    for (int i = 0; i < 16; ++i) { e[i] = __expf(p[i] - m); s += e[i]; }
    float inv = 1.f / s;
    #pragma unroll
    for (int i = 0; i < 16; ++i) p[i] = e[i] * inv;
}

// -------- fused deformable sampling + masked reduce over N -------------------
__global__ __launch_bounds__(256) void sample_reduce_kernel(
    const unsigned short* __restrict__ v,  // (BN, NV, 256) bf16
    const float* __restrict__ offatt,      // (B*Q, 384): 256 off + 128 aw
    const float* __restrict__ refp,        // (BN, Q, 2)
    const void* __restrict__ maskp,        // (BN, Q) bool
    const int* __restrict__ flag,
    unsigned short* __restrict__ S,        // (B*Q, 256) bf16
    float* __restrict__ cnts)              // (B*Q)
{
    __shared__ int4   sidx[4][NHEAD][17];
    __shared__ float4 swt[4][NHEAD][17];
    __shared__ float  red[4][CDIM];
    __shared__ float  smv[4];
    const int tid  = threadIdx.x;
    const int wn   = tid >> 6;           // wave id = view n
    const int lane = tid & 63;
    const int bq   = blockIdx.x;         // B*Q index
    const int b    = bq >> 13;
    const int q    = bq & (QQ - 1);
    const int bn   = b * 4 + wn;

    const float mn = read_mask(maskp, *flag, (size_t)bn * QQ + q);
    if (lane == 0) smv[wn] = mn;

    const float* oa = offatt + (size_t)bq * 384;
    const float rx = refp[((size_t)bn * QQ + q) * 2 + 0];
    const float ry = refp[((size_t)bn * QQ + q) * 2 + 1];

    // ---- phase 1 (unconditional): 2 combos per lane ----
    #pragma unroll
    for (int cc = 0; cc < 2; ++cc) {
        const int c = lane + cc * 64;        // c = h*16 + l*4 + p
        const int hcomb = c >> 4;
        const int pcomb = c & 15;
        const int l = (c >> 2) & 3;
        const int hh = 64 >> l;
        const int ww = 112 >> l;
        const int s  = (l > 0 ? 7168 : 0) + (l > 1 ? 1792 : 0) + (l > 2 ? 448 : 0);
        const float offx = oa[c * 2 + 0];
        const float offy = oa[c * 2 + 1];
        const float aw   = oa[256 + c];
        const float x = rx * (float)ww - 0.5f + offx;
        const float y = ry * (float)hh - 0.5f + offy;
        const float x0f = floorf(x), y0f = floorf(y);
        const float lx = x - x0f, ly = y - y0f;
        const int x0 = (int)x0f, y0 = (int)y0f;
        const int x1 = x0 + 1,  y1 = y0 + 1;
        const bool vx0 = (x0 >= 0) & (x0 < ww);
        const bool vx1 = (x1 >= 0) & (x1 < ww);
        const bool vy0 = (y0 >= 0) & (y0 < hh);
        const bool vy1 = (y1 >= 0) & (y1 < hh);
        const int xc0 = min(max(x0, 0), ww - 1);
        const int xc1 = min(max(x1, 0), ww - 1);
        const int yc0 = min(max(y0, 0), hh - 1);
        const int yc1 = min(max(y1, 0), hh - 1);
        float w00 = (1.f - ly) * (1.f - lx) * aw;
        float w01 = (1.f - ly) * lx * aw;
        float w10 = ly * (1.f - lx) * aw;
        float w11 = ly * lx * aw;
        w00 = (vy0 & vx0) ? w00 : 0.f;
        w01 = (vy0 & vx1) ? w01 : 0.f;
        w10 = (vy1 & vx0) ? w10 : 0.f;
        w11 = (vy1 & vx1) ? w11 : 0.f;
        sidx[wn][hcomb][pcomb] = make_int4(s + yc0 * ww + xc0, s + yc0 * ww + xc1,
                                           s + yc1 * ww + xc0, s + yc1 * ww + xc1);
        swt[wn][hcomb][pcomb]  = make_float4(w00, w01, w10, w11);
    }
    __syncthreads();

    // ---- phase 2 (live waves only): gather. lane = h*8 + d4 ----
    float4 acc = make_float4(0.f, 0.f, 0.f, 0.f);
    if (mn != 0.f) {
        const int h  = lane >> 3;
        const int d4 = lane & 7;
        const int laneoff = h * 8 + d4;  // uint2 units within pixel
        const uint2* vb = (const uint2*)(v + (size_t)bn * NV * CDIM);
        #pragma unroll 4
        for (int p = 0; p < 16; ++p) {
            const int4   id = sidx[wn][h][p];
            const float4 wt = swt[wn][h][p];
            const uint2 g00 = vb[(size_t)(id.x * 64 + laneoff)];
            const uint2 g01 = vb[(size_t)(id.y * 64 + laneoff)];
            const uint2 g10 = vb[(size_t)(id.z * 64 + laneoff)];
            const uint2 g11 = vb[(size_t)(id.w * 64 + laneoff)];
            #define BFLO(u) __uint_as_float((u) << 16)
            #define BFHI(u) __uint_as_float((u) & 0xffff0000u)
            acc.x += wt.x * BFLO(g00.x) + wt.y * BFLO(g01.x) + wt.z * BFLO(g10.x) + wt.w * BFLO(g11.x);
            acc.y += wt.x * BFHI(g00.x) + wt.y * BFHI(g01.x) + wt.z * BFHI(g10.x) + wt.w * BFHI(g11.x);
            acc.z += wt.x * BFLO(g00.y) + wt.y * BFLO(g01.y) + wt.z * BFLO(g10.y) + wt.w * BFLO(g11.y);
            acc.w += wt.x * BFHI(g00.y) + wt.y * BFHI(g01.y) + wt.z * BFHI(g10.y) + wt.w * BFHI(g11.y);
            #undef BFLO
            #undef BFHI
        }
    }
    *(float4*)&red[wn][lane * 4] = acc;
    __syncthreads();

    const float ssum = red[0][tid] + red[1][tid] + red[2][tid] + red[3][tid];
    S[(size_t)bq * CDIM + tid] = f2bf(ssum);
    if (tid == 0) cnts[bq] = smv[0] + smv[1] + smv[2] + smv[3];
}

extern "C" void kernel_launch(void* const* d_in, const int* in_sizes, int n_in,
                              void* d_out, int out_size, void* d_ws, size_t ws_size,
                              hipStream_t stream)
{
    (void)in_sizes; (void)n_in; (void)out_size; (void)ws_size;
    const float* query = (const float*)d_in[0];   // (16384,256)
    const float* value = (const float*)d_in[1];   // (8,9520,256)
    const float* refp  = (const float*)d_in[2];   // (8,8192,2)
    const void*  maskp = d_in[3];                 // (8,8192) bool
    const float* Wv    = (const float*)d_in[6];
    const float* bv    = (const float*)d_in[7];
    const float* Woff  = (const float*)d_in[8];   // (256,256)
    const float* boff  = (const float*)d_in[9];
    const float* Watt  = (const float*)d_in[10];  // (256,128)
    const float* batt  = (const float*)d_in[11];
    const float* Wo    = (const float*)d_in[12];
    const float* bo    = (const float*)d_in[13];
    float* out = (float*)d_out;
    char* ws = (char*)d_ws;

    // workspace layout (bytes)
    unsigned short* v_bf16  = (unsigned short*)(ws + 0);          // 38,993,920
    unsigned short* v_proj  = (unsigned short*)(ws + 38993920);   // 38,993,920
    float*          offatt  = (float*)(ws + 77987840);            // 25,165,824
    unsigned short* S_bf16  = (unsigned short*)(ws + 103153664);  //  8,388,608
    unsigned short* q_bf16  = (unsigned short*)(ws + 111542272);  //  8,388,608
    unsigned short* Wt_v    = (unsigned short*)(ws + 119930880);  //    131,072
    unsigned short* Wt_oa   = (unsigned short*)(ws + 120061952);  //    196,608
    unsigned short* Wt_o    = (unsigned short*)(ws + 120258560);  //    131,072
    float*          bias_oa = (float*)(ws + 120389632);           //      1,536
    float*          cnts    = (float*)(ws + 120391168);           //     65,536
    int*            flag    = (int*)(ws + 120456704);             //          4

    detect_mask_kernel<<<1, 256, 0, stream>>>((const unsigned int*)maskp, flag);

    // packs
    pack_bf16_kernel<<<2048, 256, 0, stream>>>(
        (const float4*)value, (ushort4*)v_bf16, 76160 * 256 / 4);
    pack_bf16_kernel<<<2048, 256, 0, stream>>>(
        (const float4*)query, (ushort4*)q_bf16, 16384 * 256 / 4);
    pack_wt_kernel<<<256, 256, 0, stream>>>(Wv, 256, nullptr, Wt_v, nullptr);
    pack_wt_kernel<<<256, 256, 0, stream>>>(Woff, 256, boff, Wt_oa, bias_oa);
    pack_wt_kernel<<<128, 256, 0, stream>>>(Watt, 128, batt, Wt_oa + 256 * 256, bias_oa + 256);
    pack_wt_kernel<<<256, 256, 0, stream>>>(Wo, 256, nullptr, Wt_o, nullptr);

    // v_proj = bf16(value @ Wv + bv)   (76160 x 256 x 256)
    mfma_gemm_kernel<EP_BIAS_BF16><<<dim3(595, 2), 256, 0, stream>>>(
        v_bf16, Wt_v, bv, v_proj, CDIM, nullptr, nullptr, nullptr);

    // offatt = query @ [Woff|Watt] + [boff|batt]   (16384 x 384 x 256), ldc=384
    mfma_gemm_kernel<EP_BIAS_F32><<<dim3(128, 3), 256, 0, stream>>>(
        q_bf16, Wt_oa, bias_oa, offatt, 384, nullptr, nullptr, nullptr);

    softmax_kernel<<<512, 256, 0, stream>>>(offatt);

    // fused sampling + masked reduce over views -> S (bf16), cnts
    sample_reduce_kernel<<<16384, 256, 0, stream>>>(
        v_proj, offatt, refp, maskp, flag, S_bf16, cnts);

    // out = (sm*(query+bo) + S@Wo) / max(sm,1)   (16384 x 256 x 256)
    mfma_gemm_kernel<EP_WO_FINAL><<<dim3(128, 2), 256, 0, stream>>>(
        S_bf16, Wt_o, nullptr, out, CDIM, query, bo, cnts);
}

// Round 6
// 220.024 us; speedup vs baseline: 3.4060x; 1.1537x over previous
//
#include <hip/hip_runtime.h>
#include <cstdint>
#include <cstddef>

// Problem constants (fixed by setup_inputs)
#define QQ 8192       // Z*Y*X
#define CDIM 256
#define NV 9520
#define NLVL 4
#define NPTS 4
#define NHEAD 8
// levels: (h,w) = (64,112),(32,56),(16,28),(8,14); starts 0,7168,8960,9408

typedef __attribute__((ext_vector_type(8))) short short8;
typedef __attribute__((ext_vector_type(4))) float f32x4;

__device__ __forceinline__ unsigned short f2bf(float f)
{
    unsigned u = __float_as_uint(f);
    unsigned r = (u + 0x7fffu + ((u >> 16) & 1u)) >> 16;   // RNE
    return (unsigned short)r;
}
__device__ __forceinline__ unsigned pk2bf(float a, float b)
{
    return (unsigned)f2bf(a) | ((unsigned)f2bf(b) << 16);
}

// ---- all weight transposes + bias concat in ONE kernel ----------------------
// grid 896: [0,256) Wt_v; [256,512) Wt_oa(off); [512,640) Wt_oa(att); [640,896) Wt_o
__global__ void pack_weights_kernel(
    const float* __restrict__ Wv,
    const float* __restrict__ Woff, const float* __restrict__ boff,
    const float* __restrict__ Watt, const float* __restrict__ batt,
    const float* __restrict__ Wo,
    unsigned short* __restrict__ Wt_v,
    unsigned short* __restrict__ Wt_oa,
    unsigned short* __restrict__ Wt_o,
    float* __restrict__ bias_oa)
{
    const int n = blockIdx.x, k = threadIdx.x;
    if (n < 256) {
        Wt_v[n * 256 + k] = f2bf(Wv[(size_t)k * 256 + n]);
    } else if (n < 512) {
        const int c = n - 256;
        Wt_oa[c * 256 + k] = f2bf(Woff[(size_t)k * 256 + c]);
        if (k == 0) bias_oa[c] = boff[c];
    } else if (n < 640) {
        const int c = n - 512;
        Wt_oa[(256 + c) * 256 + k] = f2bf(Watt[(size_t)k * 128 + c]);
        if (k == 0) bias_oa[256 + c] = batt[c];
    } else {
        const int c = n - 640;
        Wt_o[c * 256 + k] = f2bf(Wo[(size_t)k * 256 + c]);
    }
}

// ---------------- MFMA bf16 GEMM: C = A(Mx256) @ Bt^T + epilogue -------------
// A: (M,256) row-major, bf16 (AF32=false) or f32 (AF32=true, converted in reg).
// Bt: (N,256) bf16 row-major (transposed weights).
// Tile 128x128, 4 waves (2x2), wave tile 64x64 = 4x4 frags of 16x16x32.
// LDS: As/Bs 128 rows x 64 bf16 (128B rows), 16B-block XOR swizzle kb^(row&7).
enum { EP_BIAS_BF16 = 0, EP_BIAS_F32 = 1, EP_WO_FINAL = 2 };

template <int EP, bool AF32>
__global__ __launch_bounds__(256) void mfma_gemm_kernel(
    const void* __restrict__ Ap,
    const unsigned short* __restrict__ Bt,
    const float* __restrict__ bias,
    void* __restrict__ C, int ldc,
    const float* __restrict__ query,
    const float* __restrict__ bo,
    const float* __restrict__ cnts)
{
    __shared__ unsigned short As[128 * 64];
    __shared__ unsigned short Bs[128 * 64];
    const int tid  = threadIdx.x;
    const int lane = tid & 63;
    const int wave = tid >> 6;
    const int wm = wave >> 1, wn = wave & 1;
    const int lr = lane & 15, g = lane >> 4;      // g in 0..3
    const int m0 = blockIdx.x * 128, n0 = blockIdx.y * 128;

    f32x4 acc[4][4];
    #pragma unroll
    for (int mi = 0; mi < 4; ++mi)
        #pragma unroll
        for (int ni = 0; ni < 4; ++ni)
            acc[mi][ni] = (f32x4){0.f, 0.f, 0.f, 0.f};

    const unsigned short* gB = Bt + (size_t)n0 * 256;

    for (int kt = 0; kt < 4; ++kt) {              // K = 256 = 4 x 64
        uint4 ra[4], rb[4];
        #pragma unroll
        for (int it = 0; it < 4; ++it) {
            const int fb  = it * 256 + tid;       // 1024 16B-blocks per tile
            const int row = fb >> 3, kb = fb & 7;
            if constexpr (AF32) {
                const float* gA = (const float*)Ap + (size_t)m0 * 256;
                const float* p = gA + (size_t)row * 256 + kt * 64 + kb * 8;
                float4 f0 = *(const float4*)p;
                float4 f1 = *(const float4*)(p + 4);
                ra[it] = make_uint4(pk2bf(f0.x, f0.y), pk2bf(f0.z, f0.w),
                                    pk2bf(f1.x, f1.y), pk2bf(f1.z, f1.w));
            } else {
                const unsigned short* gA = (const unsigned short*)Ap + (size_t)m0 * 256;
                ra[it] = *(const uint4*)(gA + (size_t)row * 256 + kt * 64 + kb * 8);
            }
            rb[it] = *(const uint4*)(gB + (size_t)row * 256 + kt * 64 + kb * 8);
        }
        __syncthreads();   // previous tile's LDS reads drained
        #pragma unroll
        for (int it = 0; it < 4; ++it) {
            const int fb  = it * 256 + tid;
            const int row = fb >> 3, kb = fb & 7;
            const int sw  = (kb ^ (row & 7)) << 3;   // ushort units (16B blocks)
            *(uint4*)&As[row * 64 + sw] = ra[it];
            *(uint4*)&Bs[row * 64 + sw] = rb[it];
        }
        __syncthreads();
        #pragma unroll
        for (int kk = 0; kk < 2; ++kk) {
            const int kb = kk * 4 + g;
            short8 af[4], bf[4];
            #pragma unroll
            for (int mi = 0; mi < 4; ++mi) {
                const int row = wm * 64 + mi * 16 + lr;
                af[mi] = *(const short8*)&As[row * 64 + ((kb ^ (row & 7)) << 3)];
            }
            #pragma unroll
            for (int ni = 0; ni < 4; ++ni) {
                const int row = wn * 64 + ni * 16 + lr;
                bf[ni] = *(const short8*)&Bs[row * 64 + ((kb ^ (row & 7)) << 3)];
            }
            #pragma unroll
            for (int mi = 0; mi < 4; ++mi)
                #pragma unroll
                for (int ni = 0; ni < 4; ++ni)
                    acc[mi][ni] = __builtin_amdgcn_mfma_f32_16x16x32_bf16(
                        af[mi], bf[ni], acc[mi][ni], 0, 0, 0);
        }
    }

    // ---- epilogue.  C/D layout: col = lane&15, row = (lane>>4)*4 + reg ----
    if constexpr (EP == EP_BIAS_BF16 || EP == EP_BIAS_F32) {
        float bcol[4];
        #pragma unroll
        for (int ni = 0; ni < 4; ++ni)
            bcol[ni] = bias[n0 + wn * 64 + ni * 16 + lr];
        #pragma unroll
        for (int mi = 0; mi < 4; ++mi) {
            #pragma unroll
            for (int j = 0; j < 4; ++j) {
                const int gm = m0 + wm * 64 + mi * 16 + g * 4 + j;
                #pragma unroll
                for (int ni = 0; ni < 4; ++ni) {
                    const int gn = n0 + wn * 64 + ni * 16 + lr;
                    const float r = acc[mi][ni][j] + bcol[ni];
                    if constexpr (EP == EP_BIAS_BF16)
                        ((unsigned short*)C)[(size_t)gm * ldc + gn] = f2bf(r);
                    else
                        ((float*)C)[(size_t)gm * ldc + gn] = r;
                }
            }
        }
    } else {   // EP_WO_FINAL: out = (sm*(query+bo) + acc) / max(sm,1)
        float bcol[4];
        #pragma unroll
        for (int ni = 0; ni < 4; ++ni)
            bcol[ni] = bo[n0 + wn * 64 + ni * 16 + lr];
        #pragma unroll
        for (int mi = 0; mi < 4; ++mi) {
            #pragma unroll
            for (int j = 0; j < 4; ++j) {
                const int gm = m0 + wm * 64 + mi * 16 + g * 4 + j;
                const float sm = cnts[gm];
                const float inv = 1.f / fmaxf(sm, 1.f);
                #pragma unroll
                for (int ni = 0; ni < 4; ++ni) {
                    const int gn = n0 + wn * 64 + ni * 16 + lr;
                    const float qv = query[(size_t)gm * CDIM + gn] + bcol[ni];
                    ((float*)C)[(size_t)gm * ldc + gn] =
                        (sm * qv + acc[mi][ni][j]) * inv;
                }
            }
        }
    }
}

// ---------------- mask dtype sniffer (bool-as-u8 vs i32 vs f32) --------------
__global__ void detect_mask_kernel(const unsigned int* __restrict__ m, int* flag)
{
    __shared__ int notI32, notF32;
    if (threadIdx.x == 0) { notI32 = 0; notF32 = 0; }
    __syncthreads();
    for (int i = threadIdx.x; i < 1024; i += 256) {
        unsigned v = m[i];
        if (v > 1u) notI32 = 1;
        if (v != 0u && v != 0x3F800000u) notF32 = 1;
    }
    __syncthreads();
    if (threadIdx.x == 0) *flag = (!notI32) ? 1 : ((!notF32) ? 2 : 0);
}

__device__ __forceinline__ float read_mask(const void* p, int f, size_t i)
{
    if (f == 1) return (float)((const int*)p)[i];
    if (f == 2) return ((const float*)p)[i];
    return (float)((const unsigned char*)p)[i];
}

// -------- fused softmax + deformable sampling + masked reduce over N ---------
// One block per (b,q); wave n (0..3) handles view bn = b*4+n.
// Phase 1 (all waves): softmax over each head's 16 logits via 16-lane shfl
//   groups; 128 (h,l,p) combos -> LDS {int4 idx, float4 weight}.
// Phase 2 (live waves): lanes 0-31 = corners {00,10}, lanes 32-63 = {01,11};
//   4 lanes x 16B per head -> 2 dwordx4 loads per point (8 bf16 ch each).
// Combine: shfl_xor(32) half-wave sum, LDS cross-wave sum -> S (bf16), cnts.
__global__ __launch_bounds__(256) void sample_reduce_kernel(
    const unsigned short* __restrict__ v,  // (BN, NV, 256) bf16
    const float* __restrict__ offatt,      // (B*Q, 384): 256 off + 128 att logits
    const float* __restrict__ refp,        // (BN, Q, 2)
    const void* __restrict__ maskp,        // (BN, Q) bool
    const int* __restrict__ flag,
    unsigned short* __restrict__ S,        // (B*Q, 256) bf16
    float* __restrict__ cnts)              // (B*Q)
{
    __shared__ int4   sidx[4][NHEAD][17];
    __shared__ float4 swt[4][NHEAD][17];
    __shared__ float  red[4][CDIM];
    __shared__ float  smv[4];
    const int tid  = threadIdx.x;
    const int wn   = tid >> 6;           // wave id = view n
    const int lane = tid & 63;
    const int bq   = blockIdx.x;         // B*Q index
    const int b    = bq >> 13;
    const int q    = bq & (QQ - 1);
    const int bn   = b * 4 + wn;

    const float mn = read_mask(maskp, *flag, (size_t)bn * QQ + q);
    if (lane == 0) smv[wn] = mn;

    const float* oa = offatt + (size_t)bq * 384;
    const float rx = refp[((size_t)bn * QQ + q) * 2 + 0];
    const float ry = refp[((size_t)bn * QQ + q) * 2 + 1];

    // ---- phase 1 (unconditional): 2 combos per lane; inline softmax ----
    #pragma unroll
    for (int cc = 0; cc < 2; ++cc) {
        const int c = lane + cc * 64;        // c = h*16 + l*4 + p
        const int hcomb = c >> 4;
        const int pcomb = c & 15;
        const int l = (c >> 2) & 3;
        const int hh = 64 >> l;
        const int ww = 112 >> l;
        const int s  = (l > 0 ? 7168 : 0) + (l > 1 ? 1792 : 0) + (l > 2 ? 448 : 0);
        const float offx = oa[c * 2 + 0];
        const float offy = oa[c * 2 + 1];
        // softmax over the 16 lanes of this head-group (lanes h*16..h*16+15)
        const float logit = oa[256 + c];
        float mx = logit;
        #pragma unroll
        for (int d = 1; d < 16; d <<= 1) mx = fmaxf(mx, __shfl_xor(mx, d));
        const float e = __expf(logit - mx);
        float se = e;
        #pragma unroll
        for (int d = 1; d < 16; d <<= 1) se += __shfl_xor(se, d);
        const float aw = e / se;

        const float x = rx * (float)ww - 0.5f + offx;
        const float y = ry * (float)hh - 0.5f + offy;
        const float x0f = floorf(x), y0f = floorf(y);
        const float lx = x - x0f, ly = y - y0f;
        const int x0 = (int)x0f, y0 = (int)y0f;
        const int x1 = x0 + 1,  y1 = y0 + 1;
        const bool vx0 = (x0 >= 0) & (x0 < ww);
        const bool vx1 = (x1 >= 0) & (x1 < ww);
        const bool vy0 = (y0 >= 0) & (y0 < hh);
        const bool vy1 = (y1 >= 0) & (y1 < hh);
        const int xc0 = min(max(x0, 0), ww - 1);
        const int xc1 = min(max(x1, 0), ww - 1);
        const int yc0 = min(max(y0, 0), hh - 1);
        const int yc1 = min(max(y1, 0), hh - 1);
        float w00 = (1.f - ly) * (1.f - lx) * aw;
        float w01 = (1.f - ly) * lx * aw;
        float w10 = ly * (1.f - lx) * aw;
        float w11 = ly * lx * aw;
        w00 = (vy0 & vx0) ? w00 : 0.f;
        w01 = (vy0 & vx1) ? w01 : 0.f;
        w10 = (vy1 & vx0) ? w10 : 0.f;
        w11 = (vy1 & vx1) ? w11 : 0.f;
        sidx[wn][hcomb][pcomb] = make_int4(s + yc0 * ww + xc0, s + yc0 * ww + xc1,
                                           s + yc1 * ww + xc0, s + yc1 * ww + xc1);
        swt[wn][hcomb][pcomb]  = make_float4(w00, w01, w10, w11);
    }
    __syncthreads();

    // ---- phase 2 (live waves only): 2 corners per load instruction ----
    // lane = half*32 + h*4 + dq;  half 0: corners {00,10}, half 1: {01,11}
    const int half = lane >> 5;
    const int h8   = (lane >> 2) & 7;
    const int dq   = lane & 3;
    float acc[8] = {0.f, 0.f, 0.f, 0.f, 0.f, 0.f, 0.f, 0.f};
    if (mn != 0.f) {
        const uint4* vb = (const uint4*)(v + (size_t)bn * NV * CDIM);  // 32 u4/pixel
        const int lo = h8 * 4 + dq;          // uint4 offset within pixel row
        #pragma unroll 8
        for (int p = 0; p < 16; ++p) {
            const int4   id = sidx[wn][h8][p];
            const float4 wt = swt[wn][h8][p];
            const int   pixA = half ? id.y : id.x;   // corner 00 / 01
            const float wA   = half ? wt.y : wt.x;
            const int   pixB = half ? id.w : id.z;   // corner 10 / 11
            const float wB   = half ? wt.w : wt.z;
            const uint4 gA = vb[(size_t)(pixA * 32 + lo)];
            const uint4 gB = vb[(size_t)(pixB * 32 + lo)];
            #define BFLO(u) __uint_as_float((u) << 16)
            #define BFHI(u) __uint_as_float((u) & 0xffff0000u)
            acc[0] += wA * BFLO(gA.x) + wB * BFLO(gB.x);
            acc[1] += wA * BFHI(gA.x) + wB * BFHI(gB.x);
            acc[2] += wA * BFLO(gA.y) + wB * BFLO(gB.y);
            acc[3] += wA * BFHI(gA.y) + wB * BFHI(gB.y);
            acc[4] += wA * BFLO(gA.z) + wB * BFLO(gB.z);
            acc[5] += wA * BFHI(gA.z) + wB * BFHI(gB.z);
            acc[6] += wA * BFLO(gA.w) + wB * BFLO(gB.w);
            acc[7] += wA * BFHI(gA.w) + wB * BFHI(gB.w);
            #undef BFLO
            #undef BFHI
        }
    }
    // half-wave combine: lane & lane^32 hold same (h, dq) channel set
    #pragma unroll
    for (int j = 0; j < 8; ++j) acc[j] += __shfl_xor(acc[j], 32);
    if (half == 0) {
        const int ch = h8 * 32 + dq * 8;     // channels [ch, ch+8)
        *(float4*)&red[wn][ch]     = make_float4(acc[0], acc[1], acc[2], acc[3]);
        *(float4*)&red[wn][ch + 4] = make_float4(acc[4], acc[5], acc[6], acc[7]);
    }
    __syncthreads();

    const float ssum = red[0][tid] + red[1][tid] + red[2][tid] + red[3][tid];
    S[(size_t)bq * CDIM + tid] = f2bf(ssum);
    if (tid == 0) cnts[bq] = smv[0] + smv[1] + smv[2] + smv[3];
}

extern "C" void kernel_launch(void* const* d_in, const int* in_sizes, int n_in,
                              void* d_out, int out_size, void* d_ws, size_t ws_size,
                              hipStream_t stream)
{
    (void)in_sizes; (void)n_in; (void)out_size; (void)ws_size;
    const float* query = (const float*)d_in[0];   // (16384,256)
    const float* value = (const float*)d_in[1];   // (8,9520,256)
    const float* refp  = (const float*)d_in[2];   // (8,8192,2)
    const void*  maskp = d_in[3];                 // (8,8192) bool
    const float* Wv    = (const float*)d_in[6];
    const float* bv    = (const float*)d_in[7];
    const float* Woff  = (const float*)d_in[8];   // (256,256)
    const float* boff  = (const float*)d_in[9];
    const float* Watt  = (const float*)d_in[10];  // (256,128)
    const float* batt  = (const float*)d_in[11];
    const float* Wo    = (const float*)d_in[12];
    const float* bo    = (const float*)d_in[13];
    float* out = (float*)d_out;
    char* ws = (char*)d_ws;

    // workspace layout (bytes)
    unsigned short* v_proj  = (unsigned short*)(ws + 0);          // 38,993,920
    float*          offatt  = (float*)(ws + 38993920);            // 25,165,824
    unsigned short* S_bf16  = (unsigned short*)(ws + 64159744);   //  8,388,608
    unsigned short* Wt_v    = (unsigned short*)(ws + 72548352);   //    131,072
    unsigned short* Wt_oa   = (unsigned short*)(ws + 72679424);   //    196,608
    unsigned short* Wt_o    = (unsigned short*)(ws + 72876032);   //    131,072
    float*          bias_oa = (float*)(ws + 73007104);            //      1,536
    float*          cnts    = (float*)(ws + 73008640);            //     65,536
    int*            flag    = (int*)(ws + 73074176);              //          4

    detect_mask_kernel<<<1, 256, 0, stream>>>((const unsigned int*)maskp, flag);

    pack_weights_kernel<<<896, 256, 0, stream>>>(
        Wv, Woff, boff, Watt, batt, Wo, Wt_v, Wt_oa, Wt_o, bias_oa);

    // v_proj = bf16(value @ Wv + bv)   (76160 x 256 x 256), A = f32 value
    mfma_gemm_kernel<EP_BIAS_BF16, true><<<dim3(595, 2), 256, 0, stream>>>(
        value, Wt_v, bv, v_proj, CDIM, nullptr, nullptr, nullptr);

    // offatt = query @ [Woff|Watt] + [boff|batt]   (16384 x 384), A = f32 query
    mfma_gemm_kernel<EP_BIAS_F32, true><<<dim3(128, 3), 256, 0, stream>>>(
        query, Wt_oa, bias_oa, offatt, 384, nullptr, nullptr, nullptr);

    // fused softmax + sampling + masked reduce -> S (bf16), cnts
    sample_reduce_kernel<<<16384, 256, 0, stream>>>(
        v_proj, offatt, refp, maskp, flag, S_bf16, cnts);

    // out = (sm*(query+bo) + S@Wo) / max(sm,1)   (16384 x 256 x 256)
    mfma_gemm_kernel<EP_WO_FINAL, false><<<dim3(128, 2), 256, 0, stream>>>(
        S_bf16, Wt_o, nullptr, out, CDIM, query, bo, cnts);
}

// Round 7
// 218.524 us; speedup vs baseline: 3.4294x; 1.0069x over previous
//
#include <hip/hip_runtime.h>
#include <cstdint>
#include <cstddef>

// Problem constants (fixed by setup_inputs)
#define QQ 8192       // Z*Y*X
#define CDIM 256
#define NV 9520
#define NLVL 4
#define NPTS 4
#define NHEAD 8
// levels: (h,w) = (64,112),(32,56),(16,28),(8,14); starts 0,7168,8960,9408

typedef __attribute__((ext_vector_type(8))) short short8;
typedef __attribute__((ext_vector_type(4))) float f32x4;

__device__ __forceinline__ unsigned short f2bf(float f)
{
    unsigned u = __float_as_uint(f);
    unsigned r = (u + 0x7fffu + ((u >> 16) & 1u)) >> 16;   // RNE
    return (unsigned short)r;
}
__device__ __forceinline__ unsigned pk2bf(float a, float b)
{
    return (unsigned)f2bf(a) | ((unsigned)f2bf(b) << 16);
}

// ---- all weight transposes + bias concat in ONE kernel ----------------------
// grid 896: [0,256) Wt_v; [256,512) Wt_oa(off); [512,640) Wt_oa(att); [640,896) Wt_o
__global__ void pack_weights_kernel(
    const float* __restrict__ Wv,
    const float* __restrict__ Woff, const float* __restrict__ boff,
    const float* __restrict__ Watt, const float* __restrict__ batt,
    const float* __restrict__ Wo,
    unsigned short* __restrict__ Wt_v,
    unsigned short* __restrict__ Wt_oa,
    unsigned short* __restrict__ Wt_o,
    float* __restrict__ bias_oa)
{
    const int n = blockIdx.x, k = threadIdx.x;
    if (n < 256) {
        Wt_v[n * 256 + k] = f2bf(Wv[(size_t)k * 256 + n]);
    } else if (n < 512) {
        const int c = n - 256;
        Wt_oa[c * 256 + k] = f2bf(Woff[(size_t)k * 256 + c]);
        if (k == 0) bias_oa[c] = boff[c];
    } else if (n < 640) {
        const int c = n - 512;
        Wt_oa[(256 + c) * 256 + k] = f2bf(Watt[(size_t)k * 128 + c]);
        if (k == 0) bias_oa[256 + c] = batt[c];
    } else {
        const int c = n - 640;
        Wt_o[c * 256 + k] = f2bf(Wo[(size_t)k * 256 + c]);
    }
}

enum { EP_BIAS_BF16 = 0, EP_BIAS_F32 = 1, EP_WO_FINAL = 2 };

// ---------------- MFMA bf16 GEMM, tile 128x128, 256 thr (for N=384 case) -----
template <int EP, bool AF32>
__global__ __launch_bounds__(256) void mfma_gemm_kernel(
    const void* __restrict__ Ap,
    const unsigned short* __restrict__ Bt,
    const float* __restrict__ bias,
    void* __restrict__ C, int ldc,
    const float* __restrict__ query,
    const float* __restrict__ bo,
    const float* __restrict__ cnts)
{
    __shared__ unsigned short As[128 * 64];
    __shared__ unsigned short Bs[128 * 64];
    const int tid  = threadIdx.x;
    const int lane = tid & 63;
    const int wave = tid >> 6;
    const int wm = wave >> 1, wn = wave & 1;
    const int lr = lane & 15, g = lane >> 4;      // g in 0..3
    const int m0 = blockIdx.x * 128, n0 = blockIdx.y * 128;

    f32x4 acc[4][4];
    #pragma unroll
    for (int mi = 0; mi < 4; ++mi)
        #pragma unroll
        for (int ni = 0; ni < 4; ++ni)
            acc[mi][ni] = (f32x4){0.f, 0.f, 0.f, 0.f};

    const unsigned short* gB = Bt + (size_t)n0 * 256;

    for (int kt = 0; kt < 4; ++kt) {              // K = 256 = 4 x 64
        uint4 ra[4], rb[4];
        #pragma unroll
        for (int it = 0; it < 4; ++it) {
            const int fb  = it * 256 + tid;       // 1024 16B-blocks per tile
            const int row = fb >> 3, kb = fb & 7;
            if constexpr (AF32) {
                const float* gA = (const float*)Ap + (size_t)m0 * 256;
                const float* p = gA + (size_t)row * 256 + kt * 64 + kb * 8;
                float4 f0 = *(const float4*)p;
                float4 f1 = *(const float4*)(p + 4);
                ra[it] = make_uint4(pk2bf(f0.x, f0.y), pk2bf(f0.z, f0.w),
                                    pk2bf(f1.x, f1.y), pk2bf(f1.z, f1.w));
            } else {
                const unsigned short* gA = (const unsigned short*)Ap + (size_t)m0 * 256;
                ra[it] = *(const uint4*)(gA + (size_t)row * 256 + kt * 64 + kb * 8);
            }
            rb[it] = *(const uint4*)(gB + (size_t)row * 256 + kt * 64 + kb * 8);
        }
        __syncthreads();
        #pragma unroll
        for (int it = 0; it < 4; ++it) {
            const int fb  = it * 256 + tid;
            const int row = fb >> 3, kb = fb & 7;
            const int sw  = (kb ^ (row & 7)) << 3;   // ushort units (16B blocks)
            *(uint4*)&As[row * 64 + sw] = ra[it];
            *(uint4*)&Bs[row * 64 + sw] = rb[it];
        }
        __syncthreads();
        #pragma unroll
        for (int kk = 0; kk < 2; ++kk) {
            const int kb = kk * 4 + g;
            short8 af[4], bf[4];
            #pragma unroll
            for (int mi = 0; mi < 4; ++mi) {
                const int row = wm * 64 + mi * 16 + lr;
                af[mi] = *(const short8*)&As[row * 64 + ((kb ^ (row & 7)) << 3)];
            }
            #pragma unroll
            for (int ni = 0; ni < 4; ++ni) {
                const int row = wn * 64 + ni * 16 + lr;
                bf[ni] = *(const short8*)&Bs[row * 64 + ((kb ^ (row & 7)) << 3)];
            }
            #pragma unroll
            for (int mi = 0; mi < 4; ++mi)
                #pragma unroll
                for (int ni = 0; ni < 4; ++ni)
                    acc[mi][ni] = __builtin_amdgcn_mfma_f32_16x16x32_bf16(
                        af[mi], bf[ni], acc[mi][ni], 0, 0, 0);
        }
    }

    float bcol[4];
    #pragma unroll
    for (int ni = 0; ni < 4; ++ni)
        bcol[ni] = bias[n0 + wn * 64 + ni * 16 + lr];
    #pragma unroll
    for (int mi = 0; mi < 4; ++mi) {
        #pragma unroll
        for (int j = 0; j < 4; ++j) {
            const int gm = m0 + wm * 64 + mi * 16 + g * 4 + j;
            #pragma unroll
            for (int ni = 0; ni < 4; ++ni) {
                const int gn = n0 + wn * 64 + ni * 16 + lr;
                const float r = acc[mi][ni][j] + bcol[ni];
                if constexpr (EP == EP_BIAS_BF16)
                    ((unsigned short*)C)[(size_t)gm * ldc + gn] = f2bf(r);
                else
                    ((float*)C)[(size_t)gm * ldc + gn] = r;
            }
        }
    }
}

// ------------ MFMA bf16 GEMM, tile 128x256 (full N), 512 thr / 8 waves -------
// A read ONCE (no column-tile re-read).  N must be 256.
template <int EP, bool AF32>
__global__ __launch_bounds__(512) void mfma_gemm256_kernel(
    const void* __restrict__ Ap,
    const unsigned short* __restrict__ Bt,
    const float* __restrict__ bias,
    void* __restrict__ C,
    const float* __restrict__ query,
    const float* __restrict__ bo,
    const float* __restrict__ cnts)
{
    __shared__ unsigned short As[128 * 64];   // 16 KB
    __shared__ unsigned short Bs[256 * 64];   // 32 KB
    const int tid  = threadIdx.x;
    const int lane = tid & 63;
    const int wave = tid >> 6;                // 0..7
    const int wm = wave >> 2, wn = wave & 3;  // 2 x 4
    const int lr = lane & 15, g = lane >> 4;
    const int m0 = blockIdx.x * 128;

    f32x4 acc[4][4];
    #pragma unroll
    for (int mi = 0; mi < 4; ++mi)
        #pragma unroll
        for (int ni = 0; ni < 4; ++ni)
            acc[mi][ni] = (f32x4){0.f, 0.f, 0.f, 0.f};

    for (int kt = 0; kt < 4; ++kt) {          // K = 256 = 4 x 64
        uint4 ra[2], rb[4];
        #pragma unroll
        for (int it = 0; it < 2; ++it) {      // A: 1024 blocks / 512 thr
            const int fb  = it * 512 + tid;
            const int row = fb >> 3, kb = fb & 7;
            if constexpr (AF32) {
                const float* gA = (const float*)Ap + (size_t)m0 * 256;
                const float* p = gA + (size_t)row * 256 + kt * 64 + kb * 8;
                float4 f0 = *(const float4*)p;
                float4 f1 = *(const float4*)(p + 4);
                ra[it] = make_uint4(pk2bf(f0.x, f0.y), pk2bf(f0.z, f0.w),
                                    pk2bf(f1.x, f1.y), pk2bf(f1.z, f1.w));
            } else {
                const unsigned short* gA = (const unsigned short*)Ap + (size_t)m0 * 256;
                ra[it] = *(const uint4*)(gA + (size_t)row * 256 + kt * 64 + kb * 8);
            }
        }
        #pragma unroll
        for (int it = 0; it < 4; ++it) {      // B: 2048 blocks / 512 thr
            const int fb  = it * 512 + tid;
            const int row = fb >> 3, kb = fb & 7;
            rb[it] = *(const uint4*)(Bt + (size_t)row * 256 + kt * 64 + kb * 8);
        }
        __syncthreads();
        #pragma unroll
        for (int it = 0; it < 2; ++it) {
            const int fb  = it * 512 + tid;
            const int row = fb >> 3, kb = fb & 7;
            *(uint4*)&As[row * 64 + ((kb ^ (row & 7)) << 3)] = ra[it];
        }
        #pragma unroll
        for (int it = 0; it < 4; ++it) {
            const int fb  = it * 512 + tid;
            const int row = fb >> 3, kb = fb & 7;
            *(uint4*)&Bs[row * 64 + ((kb ^ (row & 7)) << 3)] = rb[it];
        }
        __syncthreads();
        #pragma unroll
        for (int kk = 0; kk < 2; ++kk) {
            const int kb = kk * 4 + g;
            short8 af[4], bf[4];
            #pragma unroll
            for (int mi = 0; mi < 4; ++mi) {
                const int row = wm * 64 + mi * 16 + lr;
                af[mi] = *(const short8*)&As[row * 64 + ((kb ^ (row & 7)) << 3)];
            }
            #pragma unroll
            for (int ni = 0; ni < 4; ++ni) {
                const int row = wn * 64 + ni * 16 + lr;
                bf[ni] = *(const short8*)&Bs[row * 64 + ((kb ^ (row & 7)) << 3)];
            }
            #pragma unroll
            for (int mi = 0; mi < 4; ++mi)
                #pragma unroll
                for (int ni = 0; ni < 4; ++ni)
                    acc[mi][ni] = __builtin_amdgcn_mfma_f32_16x16x32_bf16(
                        af[mi], bf[ni], acc[mi][ni], 0, 0, 0);
        }
    }

    float bcol[4];
    #pragma unroll
    for (int ni = 0; ni < 4; ++ni)
        bcol[ni] = (EP == EP_WO_FINAL ? bo : bias)[wn * 64 + ni * 16 + lr];
    #pragma unroll
    for (int mi = 0; mi < 4; ++mi) {
        #pragma unroll
        for (int j = 0; j < 4; ++j) {
            const int gm = m0 + wm * 64 + mi * 16 + g * 4 + j;
            if constexpr (EP == EP_WO_FINAL) {
                const float sm = cnts[gm];
                const float inv = 1.f / fmaxf(sm, 1.f);
                #pragma unroll
                for (int ni = 0; ni < 4; ++ni) {
                    const int gn = wn * 64 + ni * 16 + lr;
                    const float qv = query[(size_t)gm * CDIM + gn] + bcol[ni];
                    ((float*)C)[(size_t)gm * CDIM + gn] =
                        (sm * qv + acc[mi][ni][j]) * inv;
                }
            } else {
                #pragma unroll
                for (int ni = 0; ni < 4; ++ni) {
                    const int gn = wn * 64 + ni * 16 + lr;
                    const float r = acc[mi][ni][j] + bcol[ni];
                    if constexpr (EP == EP_BIAS_BF16)
                        ((unsigned short*)C)[(size_t)gm * CDIM + gn] = f2bf(r);
                    else
                        ((float*)C)[(size_t)gm * CDIM + gn] = r;
                }
            }
        }
    }
}

// ---------------- mask dtype sniffer (bool-as-u8 vs i32 vs f32) --------------
__global__ void detect_mask_kernel(const unsigned int* __restrict__ m, int* flag)
{
    __shared__ int notI32, notF32;
    if (threadIdx.x == 0) { notI32 = 0; notF32 = 0; }
    __syncthreads();
    for (int i = threadIdx.x; i < 1024; i += 256) {
        unsigned v = m[i];
        if (v > 1u) notI32 = 1;
        if (v != 0u && v != 0x3F800000u) notF32 = 1;
    }
    __syncthreads();
    if (threadIdx.x == 0) *flag = (!notI32) ? 1 : ((!notF32) ? 2 : 0);
}

__device__ __forceinline__ float read_mask(const void* p, int f, size_t i)
{
    if (f == 1) return (float)((const int*)p)[i];
    if (f == 2) return ((const float*)p)[i];
    return (float)((const unsigned char*)p)[i];
}

// -------- fused softmax + deformable sampling + masked reduce over N ---------
// One block per (b,q); wave n (0..3) handles view bn = b*4+n.
// Phase 1 (per wave): inline softmax via 16-lane shfl groups; 128 (h,l,p)
//   combos -> LDS {int4 idx, float4 weight}.  (intra-wave: no barrier needed)
// Phase 2 (live waves): lane = h*8+d4 gathers uint2 (4 bf16 ch) per corner.
// Reduce: LDS cross-wave sum -> S (bf16), cnts.
__global__ __launch_bounds__(256) void sample_reduce_kernel(
    const unsigned short* __restrict__ v,  // (BN, NV, 256) bf16
    const float* __restrict__ offatt,      // (B*Q, 384): 256 off + 128 att logits
    const float* __restrict__ refp,        // (BN, Q, 2)
    const void* __restrict__ maskp,        // (BN, Q) bool
    const int* __restrict__ flag,
    unsigned short* __restrict__ S,        // (B*Q, 256) bf16
    float* __restrict__ cnts)              // (B*Q)
{
    __shared__ int4   sidx[4][NHEAD][17];
    __shared__ float4 swt[4][NHEAD][17];
    __shared__ float  red[4][CDIM];
    __shared__ float  smv[4];
    const int tid  = threadIdx.x;
    const int wn   = tid >> 6;           // wave id = view n
    const int lane = tid & 63;
    const int bq   = blockIdx.x;         // B*Q index
    const int b    = bq >> 13;
    const int q    = bq & (QQ - 1);
    const int bn   = b * 4 + wn;

    const float mn = read_mask(maskp, *flag, (size_t)bn * QQ + q);
    if (lane == 0) smv[wn] = mn;

    const float* oa = offatt + (size_t)bq * 384;
    const float rx = refp[((size_t)bn * QQ + q) * 2 + 0];
    const float ry = refp[((size_t)bn * QQ + q) * 2 + 1];

    // ---- phase 1: 2 combos per lane; inline softmax over 16-lane groups ----
    #pragma unroll
    for (int cc = 0; cc < 2; ++cc) {
        const int c = lane + cc * 64;        // c = h*16 + l*4 + p
        const int hcomb = c >> 4;
        const int pcomb = c & 15;
        const int l = (c >> 2) & 3;
        const int hh = 64 >> l;
        const int ww = 112 >> l;
        const int s  = (l > 0 ? 7168 : 0) + (l > 1 ? 1792 : 0) + (l > 2 ? 448 : 0);
        const float offx = oa[c * 2 + 0];
        const float offy = oa[c * 2 + 1];
        const float logit = oa[256 + c];
        float mx = logit;
        #pragma unroll
        for (int d = 1; d < 16; d <<= 1) mx = fmaxf(mx, __shfl_xor(mx, d));
        const float e = __expf(logit - mx);
        float se = e;
        #pragma unroll
        for (int d = 1; d < 16; d <<= 1) se += __shfl_xor(se, d);
        const float aw = e / se;

        const float x = rx * (float)ww - 0.5f + offx;
        const float y = ry * (float)hh - 0.5f + offy;
        const float x0f = floorf(x), y0f = floorf(y);
        const float lx = x - x0f, ly = y - y0f;
        const int x0 = (int)x0f, y0 = (int)y0f;
        const int x1 = x0 + 1,  y1 = y0 + 1;
        const bool vx0 = (x0 >= 0) & (x0 < ww);
        const bool vx1 = (x1 >= 0) & (x1 < ww);
        const bool vy0 = (y0 >= 0) & (y0 < hh);
        const bool vy1 = (y1 >= 0) & (y1 < hh);
        const int xc0 = min(max(x0, 0), ww - 1);
        const int xc1 = min(max(x1, 0), ww - 1);
        const int yc0 = min(max(y0, 0), hh - 1);
        const int yc1 = min(max(y1, 0), hh - 1);
        float w00 = (1.f - ly) * (1.f - lx) * aw;
        float w01 = (1.f - ly) * lx * aw;
        float w10 = ly * (1.f - lx) * aw;
        float w11 = ly * lx * aw;
        w00 = (vy0 & vx0) ? w00 : 0.f;
        w01 = (vy0 & vx1) ? w01 : 0.f;
        w10 = (vy1 & vx0) ? w10 : 0.f;
        w11 = (vy1 & vx1) ? w11 : 0.f;
        sidx[wn][hcomb][pcomb] = make_int4(s + yc0 * ww + xc0, s + yc0 * ww + xc1,
                                           s + yc1 * ww + xc0, s + yc1 * ww + xc1);
        swt[wn][hcomb][pcomb]  = make_float4(w00, w01, w10, w11);
    }
    // no barrier: phase 2 reads only this wave's [wn] slices (intra-wave dep)

    // ---- phase 2 (live waves only): gather. lane = h*8 + d4 ----
    float4 acc = make_float4(0.f, 0.f, 0.f, 0.f);
    if (mn != 0.f) {
        const int h  = lane >> 3;
        const int d4 = lane & 7;
        const int laneoff = h * 8 + d4;  // uint2 units within pixel
        const uint2* vb = (const uint2*)(v + (size_t)bn * NV * CDIM);
        #pragma unroll 4
        for (int p = 0; p < 16; ++p) {
            const int4   id = sidx[wn][h][p];
            const float4 wt = swt[wn][h][p];
            const uint2 g00 = vb[(size_t)(id.x * 64 + laneoff)];
            const uint2 g01 = vb[(size_t)(id.y * 64 + laneoff)];
            const uint2 g10 = vb[(size_t)(id.z * 64 + laneoff)];
            const uint2 g11 = vb[(size_t)(id.w * 64 + laneoff)];
            #define BFLO(u) __uint_as_float((u) << 16)
            #define BFHI(u) __uint_as_float((u) & 0xffff0000u)
            acc.x += wt.x * BFLO(g00.x) + wt.y * BFLO(g01.x) + wt.z * BFLO(g10.x) + wt.w * BFLO(g11.x);
            acc.y += wt.x * BFHI(g00.x) + wt.y * BFHI(g01.x) + wt.z * BFHI(g10.x) + wt.w * BFHI(g11.x);
            acc.z += wt.x * BFLO(g00.y) + wt.y * BFLO(g01.y) + wt.z * BFLO(g10.y) + wt.w * BFLO(g11.y);
            acc.w += wt.x * BFHI(g00.y) + wt.y * BFHI(g01.y) + wt.z * BFHI(g10.y) + wt.w * BFHI(g11.y);
            #undef BFLO
            #undef BFHI
        }
    }
    *(float4*)&red[wn][lane * 4] = acc;
    __syncthreads();

    const float ssum = red[0][tid] + red[1][tid] + red[2][tid] + red[3][tid];
    S[(size_t)bq * CDIM + tid] = f2bf(ssum);
    if (tid == 0) cnts[bq] = smv[0] + smv[1] + smv[2] + smv[3];
}

extern "C" void kernel_launch(void* const* d_in, const int* in_sizes, int n_in,
                              void* d_out, int out_size, void* d_ws, size_t ws_size,
                              hipStream_t stream)
{
    (void)in_sizes; (void)n_in; (void)out_size; (void)ws_size;
    const float* query = (const float*)d_in[0];   // (16384,256)
    const float* value = (const float*)d_in[1];   // (8,9520,256)
    const float* refp  = (const float*)d_in[2];   // (8,8192,2)
    const void*  maskp = d_in[3];                 // (8,8192) bool
    const float* Wv    = (const float*)d_in[6];
    const float* bv    = (const float*)d_in[7];
    const float* Woff  = (const float*)d_in[8];   // (256,256)
    const float* boff  = (const float*)d_in[9];
    const float* Watt  = (const float*)d_in[10];  // (256,128)
    const float* batt  = (const float*)d_in[11];
    const float* Wo    = (const float*)d_in[12];
    const float* bo    = (const float*)d_in[13];
    float* out = (float*)d_out;
    char* ws = (char*)d_ws;

    // workspace layout (bytes)
    unsigned short* v_proj  = (unsigned short*)(ws + 0);          // 38,993,920
    float*          offatt  = (float*)(ws + 38993920);            // 25,165,824
    unsigned short* S_bf16  = (unsigned short*)(ws + 64159744);   //  8,388,608
    unsigned short* Wt_v    = (unsigned short*)(ws + 72548352);   //    131,072
    unsigned short* Wt_oa   = (unsigned short*)(ws + 72679424);   //    196,608
    unsigned short* Wt_o    = (unsigned short*)(ws + 72876032);   //    131,072
    float*          bias_oa = (float*)(ws + 73007104);            //      1,536
    float*          cnts    = (float*)(ws + 73008640);            //     65,536
    int*            flag    = (int*)(ws + 73074176);              //          4

    detect_mask_kernel<<<1, 256, 0, stream>>>((const unsigned int*)maskp, flag);

    pack_weights_kernel<<<896, 256, 0, stream>>>(
        Wv, Woff, boff, Watt, batt, Wo, Wt_v, Wt_oa, Wt_o, bias_oa);

    // v_proj = bf16(value @ Wv + bv)   (76160 x 256 x 256), A read once
    mfma_gemm256_kernel<EP_BIAS_BF16, true><<<595, 512, 0, stream>>>(
        value, Wt_v, bv, v_proj, nullptr, nullptr, nullptr);

    // offatt = query @ [Woff|Watt] + [boff|batt]   (16384 x 384), A = f32 query
    mfma_gemm_kernel<EP_BIAS_F32, true><<<dim3(128, 3), 256, 0, stream>>>(
        query, Wt_oa, bias_oa, offatt, 384, nullptr, nullptr, nullptr);

    // fused softmax + sampling + masked reduce -> S (bf16), cnts
    sample_reduce_kernel<<<16384, 256, 0, stream>>>(
        v_proj, offatt, refp, maskp, flag, S_bf16, cnts);

    // out = (sm*(query+bo) + S@Wo) / max(sm,1)   (16384 x 256 x 256)
    mfma_gemm256_kernel<EP_WO_FINAL, false><<<128, 512, 0, stream>>>(
        S_bf16, Wt_o, nullptr, out, query, bo, cnts);
}